// Round 15
// baseline (230.042 us; speedup 1.0000x reference)
//
#include <hip/hip_runtime.h>
#include <stdint.h>

typedef _Float16 f16;
typedef __attribute__((ext_vector_type(8))) f16 f16x8;
typedef __attribute__((ext_vector_type(2))) f16 h2;
typedef __attribute__((ext_vector_type(4))) float f32x4;
typedef unsigned short u16;
typedef unsigned int u32;
typedef unsigned char u8;

#define LL 1024
#define DM 512

__device__ __forceinline__ u16 f2h(float f){ return __builtin_bit_cast(u16, (f16)f); }
__device__ __forceinline__ u32 pack2(float a, float b){
  h2 v; v.x = (f16)a; v.y = (f16)b; return __builtin_bit_cast(u32, v);
}
__device__ __forceinline__ f32x4 mfma16h(f16x8 a, f16x8 b, f32x4 c){
  return __builtin_amdgcn_mfma_f32_16x16x32_f16(a, b, c, 0, 0, 0);
}

// ---- DPP 16-lane reductions (row_ror:8/4/2/1), pure VALU, no DS ----
template<int CTRL>
__device__ __forceinline__ float dpp_mov(float x){
  return __builtin_bit_cast(float,
    __builtin_amdgcn_update_dpp(0, __builtin_bit_cast(int, x), CTRL, 0xF, 0xF, true));
}
__device__ __forceinline__ float red_add16(float v){
  v += dpp_mov<0x128>(v);
  v += dpp_mov<0x124>(v);
  v += dpp_mov<0x122>(v);
  v += dpp_mov<0x121>(v);
  return v;
}
__device__ __forceinline__ float red_max16(float v){
  v = fmaxf(v, dpp_mov<0x128>(v));
  v = fmaxf(v, dpp_mov<0x124>(v));
  v = fmaxf(v, dpp_mov<0x122>(v));
  v = fmaxf(v, dpp_mov<0x121>(v));
  return v;
}

// ---------------- fp32 -> f16 convert ----------------
struct CvtArgs {
  const float* src[7];
  u16* dst[7];
  int n4[7];
};

__global__ __launch_bounds__(256) void cvt_kernel(CvtArgs a){
  int seg = blockIdx.y;
  const float4* s = (const float4*)a.src[seg];
  ushort4* d = (ushort4*)a.dst[seg];
  int n4 = a.n4[seg];
  for (int i = blockIdx.x*blockDim.x + threadIdx.x; i < n4; i += gridDim.x*blockDim.x){
    float4 v = s[i];
    ushort4 o;
    o.x = f2h(v.x); o.y = f2h(v.y); o.z = f2h(v.z); o.w = f2h(v.w);
    d[i] = o;
  }
}

// ---------------- fused QKV projection GEMM, 128x128 tile, BK=64 ----------------
// grid (64, 12): which = y>>2 (0=Q,1=K,2=V), nt = y&3.  f16 inputs.
// Staging via global_load_lds width=16; swizzle on GLOBAL source + LDS reads,
// LDS dest linear (rule #21).
struct QkvArgs {
  const u16* A[3];
  const u16* W[3];
  const float* bias[3];
  u16* dst[3];
  float scale[3];
};

__global__ __launch_bounds__(256,2) void proj_qkv(QkvArgs args){
  __shared__ u16 SM[128*128];          // 32 KiB: As(16K)+Bs(16K), reused as stage
  u16* As = SM;
  u16* Bs = SM + 128*64;
  const int tid = threadIdx.x;
  const int w = tid>>6, lane = tid&63;
  const int g = lane>>4, r16 = lane&15;
  const int wr = w>>1, wc = w&1;

  const int which = blockIdx.y>>2, nt = blockIdx.y&3;
  const bool isV = (which==2);
  const u16* A = args.A[which];
  const u16* W = args.W[which];
  const float* bias = args.bias[which];
  u16* dsth = args.dst[which];
  const float scale = args.scale[which];

  const int m0 = blockIdx.x*128, n0 = nt*128;

  f32x4 acc[4][4] = {};

  int rowc[4], slc[4];
  #pragma unroll
  for (int i=0;i<4;++i){
    int c = i*256+tid;
    rowc[i] = c>>3;
    slc[i] = (c&7) ^ ((c>>3)&7);
  }

  const int fswz = r16 & 7;

  for (int k0=0; k0<DM; k0+=64){
    #pragma unroll
    for (int i=0;i<4;++i){
      int c = i*256+tid;
      __builtin_amdgcn_global_load_lds(
        (const __attribute__((address_space(1))) void*)(A + (size_t)(m0+rowc[i])*DM + k0 + slc[i]*8),
        (__attribute__((address_space(3))) void*)(&As[c*8]), 16, 0, 0);
      __builtin_amdgcn_global_load_lds(
        (const __attribute__((address_space(1))) void*)(W + (size_t)(n0+rowc[i])*DM + k0 + slc[i]*8),
        (__attribute__((address_space(3))) void*)(&Bs[c*8]), 16, 0, 0);
    }
    __syncthreads();   // drains vmcnt -> staged LDS ready

    f16x8 af[4][2], bfr[4][2];
    #pragma unroll
    for (int mi=0; mi<4; ++mi){
      int row = wr*64 + mi*16 + r16;
      #pragma unroll
      for (int ks=0; ks<2; ++ks)
        af[mi][ks] = *(const f16x8*)(&As[row*64 + ((ks*4+g)^fswz)*8]);
    }
    #pragma unroll
    for (int ni=0; ni<4; ++ni){
      int row = wc*64 + ni*16 + r16;
      #pragma unroll
      for (int ks=0; ks<2; ++ks)
        bfr[ni][ks] = *(const f16x8*)(&Bs[row*64 + ((ks*4+g)^fswz)*8]);
    }
    if (isV){
      #pragma unroll
      for (int mi=0; mi<4; ++mi)
        #pragma unroll
        for (int ni=0; ni<4; ++ni){
          acc[mi][ni] = mfma16h(af[mi][0], bfr[ni][0], acc[mi][ni]);
          acc[mi][ni] = mfma16h(af[mi][1], bfr[ni][1], acc[mi][ni]);
        }
    } else {
      #pragma unroll
      for (int mi=0; mi<4; ++mi)
        #pragma unroll
        for (int ni=0; ni<4; ++ni){
          acc[mi][ni] = mfma16h(bfr[ni][0], af[mi][0], acc[mi][ni]);
          acc[mi][ni] = mfma16h(bfr[ni][1], af[mi][1], acc[mi][ni]);
        }
    }
    __syncthreads();   // all reads done before next stage overwrites
  }

  // ---- epilogue: stage into chunk-swizzled LDS, then coalesced stores
  if (!isV){
    #pragma unroll
    for (int mi=0; mi<4; ++mi){
      #pragma unroll
      for (int ni=0; ni<4; ++ni){
        f32x4 a = acc[mi][ni];
        int row = wr*64 + mi*16 + r16;
        int c   = wc*16 + ni*4 + g;
        float4 bv = *(const float4*)(bias + n0 + c*4);
        uint2 pk;
        pk.x = pack2((a[0]+bv.x)*scale, (a[1]+bv.y)*scale);
        pk.y = pack2((a[2]+bv.z)*scale, (a[3]+bv.w)*scale);
        *(uint2*)(&SM[row*128 + ((c ^ ((row&7)<<2))<<2)]) = pk;
      }
    }
  } else {
    #pragma unroll
    for (int mi=0; mi<4; ++mi){
      #pragma unroll
      for (int ni=0; ni<4; ++ni){
        f32x4 a = acc[mi][ni];
        int fl = wc*64 + ni*16 + r16;
        int kc = wr*16 + mi*4 + g;
        float bv = bias[n0 + fl];
        uint2 pk;
        pk.x = pack2(a[0]+bv, a[1]+bv);
        pk.y = pack2(a[2]+bv, a[3]+bv);
        *(uint2*)(&SM[fl*128 + ((kc ^ ((fl&7)<<2))<<2)]) = pk;
      }
    }
  }
  __syncthreads();

  #pragma unroll
  for (int rr=0; rr<8; ++rr){
    int row = w*32 + rr*4 + (lane>>4);
    int c0 = (lane&15)*2;
    int cs = c0 ^ ((row&7)<<2);
    uint4 v = *(const uint4*)(&SM[row*128 + (cs<<2)]);
    if (!isV){
      *(uint4*)(dsth + (size_t)(m0+row)*DM + n0 + (c0<<2)) = v;
    } else {
      int n = n0 + row;
      int hh = n>>6, d = n&63, bb = m0>>10;
      *(uint4*)(dsth + (size_t)((bb*8+hh)*64 + d)*1024 + (m0&1023) + (c0<<2)) = v;
    }
  }
}

// ---------------- out-projection GEMM, 64x128 tile, BK=64, grid (128,4) ----------------
__global__ __launch_bounds__(256,2) void proj_out(
    const u16* __restrict__ A, const u16* __restrict__ W,
    const float* __restrict__ bias, float* __restrict__ dstf)
{
  __shared__ u16 As[64*64];
  __shared__ u16 Bs[128*64];
  const int tid = threadIdx.x;
  const int w = tid>>6, lane = tid&63;
  const int g = lane>>4, r16 = lane&15;
  const int m0 = blockIdx.x*64, n0 = blockIdx.y*128;

  f32x4 acc[4][2] = {};

  int rowa[2], slota[2];
  #pragma unroll
  for (int i=0;i<2;++i){ int c = i*256+tid; rowa[i]=c>>3; slota[i]=c&7; }
  int rowb[4], slotb[4];
  #pragma unroll
  for (int i=0;i<4;++i){ int c = i*256+tid; rowb[i]=c>>3; slotb[i]=c&7; }

  uint4 ra[2], rb[4];
  #pragma unroll
  for (int i=0;i<2;++i)
    ra[i] = *(const uint4*)(A + (size_t)(m0+rowa[i])*DM + slota[i]*8);
  #pragma unroll
  for (int i=0;i<4;++i)
    rb[i] = *(const uint4*)(W + (size_t)(n0+rowb[i])*DM + slotb[i]*8);

  const int fswz = r16 & 7;

  for (int k0=0; k0<DM; k0+=64){
    __syncthreads();
    #pragma unroll
    for (int i=0;i<2;++i)
      *(uint4*)(&As[rowa[i]*64 + (slota[i]^(rowa[i]&7))*8]) = ra[i];
    #pragma unroll
    for (int i=0;i<4;++i)
      *(uint4*)(&Bs[rowb[i]*64 + (slotb[i]^(rowb[i]&7))*8]) = rb[i];
    __syncthreads();
    int kn = (k0+64 < DM) ? (k0+64) : 0;
    #pragma unroll
    for (int i=0;i<2;++i)
      ra[i] = *(const uint4*)(A + (size_t)(m0+rowa[i])*DM + kn + slota[i]*8);
    #pragma unroll
    for (int i=0;i<4;++i)
      rb[i] = *(const uint4*)(W + (size_t)(n0+rowb[i])*DM + kn + slotb[i]*8);

    f16x8 af[4][2], bfr[2][2];
    #pragma unroll
    for (int mi=0; mi<4; ++mi){
      int row = mi*16 + r16;
      #pragma unroll
      for (int ks=0; ks<2; ++ks)
        af[mi][ks] = *(const f16x8*)(&As[row*64 + ((ks*4+g)^fswz)*8]);
    }
    #pragma unroll
    for (int ni=0; ni<2; ++ni){
      int row = w*32 + ni*16 + r16;
      #pragma unroll
      for (int ks=0; ks<2; ++ks)
        bfr[ni][ks] = *(const f16x8*)(&Bs[row*64 + ((ks*4+g)^fswz)*8]);
    }
    #pragma unroll
    for (int mi=0; mi<4; ++mi)
      #pragma unroll
      for (int ni=0; ni<2; ++ni){
        acc[mi][ni] = mfma16h(bfr[ni][0], af[mi][0], acc[mi][ni]);
        acc[mi][ni] = mfma16h(bfr[ni][1], af[mi][1], acc[mi][ni]);
      }
  }

  #pragma unroll
  for (int mi=0; mi<4; ++mi){
    #pragma unroll
    for (int ni=0; ni<2; ++ni){
      int m  = m0 + mi*16 + r16;
      int nb = n0 + w*32 + ni*16 + g*4;
      float4 bv = *(const float4*)(bias + nb);
      float4 o;
      o.x = acc[mi][ni][0]+bv.x; o.y = acc[mi][ni][1]+bv.y;
      o.z = acc[mi][ni][2]+bv.z; o.w = acc[mi][ni][3]+bv.w;
      *(float4*)(dstf + (size_t)m*DM + nb) = o;
    }
  }
}

// ---------------- fused attention + entmax-1.5 (r14 + deep MLP) ----------------
// grid 2048, 512 threads (8 waves): bh = ((bid&7)<<3)|((bid>>3)&7), qb = bid>>6.
// 32 q-rows/block, S[32][1024] f16 = 64 KiB (2 blocks/CU).
// Phase A: full K working set (8 kt = 64 VGPR) loaded in one 16-load burst ->
// L2 latency (~225cy) covered by in-flight depth, not 2-deep dbuf (r11 null).
// Phase C: 3-chunk rotating 12-deep buffer (24 loads in flight), macro-static.
// Newton 5 iters + finalize. Swizzle: (row,k) at u16 off row*1024 + (k^(cc<<3)),
// cc = ((k>>6)&7) ^ (row&7).
__global__ __launch_bounds__(512,4) void attn_entmax(
    const u16* __restrict__ Qf, const u16* __restrict__ Kf,
    const u16* __restrict__ Vt, const u8* __restrict__ mask,
    u16* __restrict__ ctx)
{
  __shared__ u16 S[32*1024];   // 64 KiB

  const int tid = threadIdx.x, w = tid>>6, lane = tid&63;
  const int g = lane>>4, r16 = lane&15;
  const int bid = blockIdx.x;
  const int bh = ((bid&7)<<3) | ((bid>>3)&7);
  const int qb = bid>>6;
  const int b = bh>>3, h = bh&7;
  const int q0 = qb*32;
  const u16* Qb = Qf + ((size_t)(b*LL + q0))*DM + h*64;
  const u16* Kb = Kf + ((size_t)(b*LL))*DM + h*64;

  // ---- Phase A: S^T = K Q^T (scale folded into Q); wave w: keys [w*128,+128)
  // All 8 kt K-rows + mask words loaded up front (16 loads in flight).
  f16x8 qf[2][2];
  #pragma unroll
  for (int qi=0;qi<2;++qi){
    qf[qi][0] = *(const f16x8*)(Qb + (size_t)(qi*16 + r16)*DM + g*8);
    qf[qi][1] = *(const f16x8*)(Qb + (size_t)(qi*16 + r16)*DM + 32 + g*8);
  }
  {
    f16x8 kr0[8], kr1[8];
    u32 m4a[8];
    #pragma unroll
    for (int kt=0;kt<8;++kt){
      const u16* kp = Kb + (size_t)(w*128 + kt*16 + r16)*DM + g*8;
      kr0[kt] = *(const f16x8*)(kp);
      kr1[kt] = *(const f16x8*)(kp + 32);
      m4a[kt] = *(const u32*)(mask + b*LL + w*128 + kt*16 + g*4);
    }
    #pragma unroll
    for (int kt=0;kt<8;++kt){
      int kb = w*128 + kt*16 + g*4;
      u32 m4 = m4a[kt];
      #pragma unroll
      for (int qi=0; qi<2; ++qi){
        f32x4 acc = {};
        acc = mfma16h(kr0[kt], qf[qi][0], acc);   // reg-dim: key, col: q=r16
        acc = mfma16h(kr1[kt], qf[qi][1], acc);
        float v0 = (m4 & 0xFFu)       ? -30000.f : acc[0];
        float v1 = (m4 & 0xFF00u)     ? -30000.f : acc[1];
        float v2 = (m4 & 0xFF0000u)   ? -30000.f : acc[2];
        float v3 = (m4 & 0xFF000000u) ? -30000.f : acc[3];
        int row = qi*16 + r16;
        int cc = ((kb>>6)&7) ^ (row&7);
        uint2 pk; pk.x = pack2(v0,v1); pk.y = pack2(v2,v3);
        *(uint2*)(&S[row*LL + (kb ^ (cc<<3))]) = pk;
      }
    }
  }
  __syncthreads();

  // ---- Phase B: entmax-1.5; row = w*4+g (4 rows/wave in parallel),
  // lane r16 holds 64 contiguous keys as 32 h2; all-DPP reduces; 5 Newton iters.
  {
    const int r = w*4 + g;
    const int ccb = (r16 ^ r) & 7;
    h2 zp[32];
    #pragma unroll
    for (int c=0;c<8;++c){
      uint4 v = *(const uint4*)(&S[r*LL + ((r16*64 + c*8) ^ (ccb<<3))]);
      zp[c*4+0] = __builtin_bit_cast(h2, v.x);
      zp[c*4+1] = __builtin_bit_cast(h2, v.y);
      zp[c*4+2] = __builtin_bit_cast(h2, v.z);
      zp[c*4+3] = __builtin_bit_cast(h2, v.w);
    }
    h2 m2 = zp[0];
    #pragma unroll
    for (int t=1;t<32;++t) m2 = __builtin_elementwise_max(m2, zp[t]);
    float mx = red_max16(fmaxf((float)m2.x, (float)m2.y));

    const h2 zero2 = (h2)(f16)0;
    float lo = mx - 1.0f, hi = mx, tau = mx - 0.5f;
    #pragma unroll 1
    for (int it=0; it<5; ++it){
      f16 th = (f16)tau;
      h2 t2; t2.x = th; t2.y = th;
      h2 s1a = zero2, s1b = zero2, s2a = zero2, s2b = zero2;
      #pragma unroll
      for (int t=0;t<32;t+=2){
        h2 d0 = __builtin_elementwise_max(zp[t]   - t2, zero2);
        h2 d1 = __builtin_elementwise_max(zp[t+1] - t2, zero2);
        s1a = s1a + d0;        s1b = s1b + d1;
        s2a = s2a + d0*d0;     s2b = s2b + d1*d1;
      }
      h2 s1h = s1a + s1b, s2h = s2a + s2b;
      float s1 = red_add16((float)s1h.x + (float)s1h.y);
      float s2 = red_add16((float)s2h.x + (float)s2h.y);
      if (s2 >= 1.0f) lo = tau; else hi = tau;
      float tn = tau + (s2 - 1.0f)/(2.0f*s1);
      tau = (tn >= lo && tn < hi) ? tn : 0.5f*(lo+hi);
    }

    {
      f16 th = (f16)tau;
      h2 t2; t2.x = th; t2.y = th;
      h2 psa = zero2, psb = zero2;
      #pragma unroll
      for (int t=0;t<32;t+=2){
        h2 d0 = __builtin_elementwise_max(zp[t]   - t2, zero2);
        h2 d1 = __builtin_elementwise_max(zp[t+1] - t2, zero2);
        h2 p0 = d0*d0, p1 = d1*d1;
        zp[t] = p0; zp[t+1] = p1;
        psa = psa + p0; psb = psb + p1;
      }
      h2 ps2 = psa + psb;
      float ps = red_add16((float)ps2.x + (float)ps2.y);
      f16 iv = (f16)(1.0f/ps);
      h2 i2; i2.x = iv; i2.y = iv;
      #pragma unroll
      for (int c=0;c<8;++c){
        uint4 v;
        v.x = __builtin_bit_cast(u32, (h2)(zp[c*4+0]*i2));
        v.y = __builtin_bit_cast(u32, (h2)(zp[c*4+1]*i2));
        v.z = __builtin_bit_cast(u32, (h2)(zp[c*4+2]*i2));
        v.w = __builtin_bit_cast(u32, (h2)(zp[c*4+3]*i2));
        *(uint4*)(&S[r*LL + ((r16*64 + c*8) ^ (ccb<<3))]) = v;  // same slots read
      }
    }
  }
  __syncthreads();

  // ---- Phase C: ctx = P @ V ; wave w -> q-tile (w>>2), d-tile (w&3);
  // 3-chunk rotating 12-deep (P,V) buffer: ~24 loads in flight; setprio on MFMAs.
  const int qi = w>>2, di = w&3;
  const u16* vrow = Vt + (size_t)(bh*64 + di*16 + r16)*LL;
  const int prow = qi*16 + r16;
  f32x4 o0 = {}, o1 = {};
  {
    f16x8 p0[4],v0[4],p1[4],v1[4],p2[4],v2[4];
#define LOADC(pp,vv,grp) { \
    _Pragma("unroll") \
    for (int j=0;j<4;++j){ \
      int k = ((grp)*4+j)*32 + g*8; \
      int cc = ((k>>6)&7) ^ (prow&7); \
      pp[j] = *(const f16x8*)(&S[prow*LL + (k ^ (cc<<3))]); \
      vv[j] = *(const f16x8*)(vrow + k); \
    } }
#define MMA4(pp,vv) { \
    __builtin_amdgcn_s_setprio(1); \
    o0 = mfma16h(pp[0],vv[0],o0); o1 = mfma16h(pp[1],vv[1],o1); \
    o0 = mfma16h(pp[2],vv[2],o0); o1 = mfma16h(pp[3],vv[3],o1); \
    __builtin_amdgcn_s_setprio(0); }

    LOADC(p0,v0,0) LOADC(p1,v1,1) LOADC(p2,v2,2)
    MMA4(p0,v0) LOADC(p0,v0,3)
    MMA4(p1,v1) LOADC(p1,v1,4)
    MMA4(p2,v2) LOADC(p2,v2,5)
    MMA4(p0,v0) LOADC(p0,v0,6)
    MMA4(p1,v1) LOADC(p1,v1,7)
    MMA4(p2,v2)
    MMA4(p0,v0)
    MMA4(p1,v1)
#undef LOADC
#undef MMA4
  }
  #pragma unroll
  for (int r=0;r<4;++r){
    int q = q0 + qi*16 + g*4 + r;
    ctx[(size_t)(b*LL + q)*DM + h*64 + di*16 + r16] = f2h(o0[r] + o1[r]);
  }
}

// ---------------- launch ----------------
extern "C" void kernel_launch(void* const* d_in, const int* in_sizes, int n_in,
                              void* d_out, int out_size, void* d_ws, size_t ws_size,
                              hipStream_t stream) {
  const float* query = (const float*)d_in[0];
  const float* key   = (const float*)d_in[1];
  const float* value = (const float*)d_in[2];
  const u8*    maskp = (const u8*)d_in[3];
  const float* q_w = (const float*)d_in[4];
  const float* q_b = (const float*)d_in[5];
  const float* k_w = (const float*)d_in[6];
  const float* k_b = (const float*)d_in[7];
  const float* v_w = (const float*)d_in[8];
  const float* v_b = (const float*)d_in[9];
  const float* out_w = (const float*)d_in[10];
  const float* out_b = (const float*)d_in[11];
  float* out = (float*)d_out;

  u16* qx = (u16*)d_ws;                 // 4M f16 elems each
  u16* kx = qx + 4194304;
  u16* vx = kx + 4194304;
  u16* wq = vx + 4194304;               // 256K elems each
  u16* wk = wq + 262144;
  u16* wv = wk + 262144;
  u16* wo = wv + 262144;
  u16* Qbuf = wo + 262144;              // 4M elems each
  u16* Kbuf = Qbuf + 4194304;
  u16* Vt   = Kbuf + 4194304;
  u16* ctxb = Vt + 4194304;

  CvtArgs ca;
  ca.src[0]=query; ca.dst[0]=qx; ca.n4[0]=8*LL*DM/4;
  ca.src[1]=key;   ca.dst[1]=kx; ca.n4[1]=8*LL*DM/4;
  ca.src[2]=value; ca.dst[2]=vx; ca.n4[2]=8*LL*DM/4;
  ca.src[3]=q_w;   ca.dst[3]=wq; ca.n4[3]=DM*DM/4;
  ca.src[4]=k_w;   ca.dst[4]=wk; ca.n4[4]=DM*DM/4;
  ca.src[5]=v_w;   ca.dst[5]=wv; ca.n4[5]=DM*DM/4;
  ca.src[6]=out_w; ca.dst[6]=wo; ca.n4[6]=DM*DM/4;
  cvt_kernel<<<dim3(512,7),256,0,stream>>>(ca);

  QkvArgs qa;
  qa.A[0]=qx; qa.A[1]=kx; qa.A[2]=vx;
  qa.W[0]=wq; qa.W[1]=wk; qa.W[2]=wv;
  qa.bias[0]=q_b; qa.bias[1]=k_b; qa.bias[2]=v_b;
  qa.dst[0]=Qbuf; qa.dst[1]=Kbuf; qa.dst[2]=Vt;
  qa.scale[0]=0.0625f; qa.scale[1]=1.0f; qa.scale[2]=1.0f; // 1/8 (dh^-0.5) * 1/2 on Q

  proj_qkv<<<dim3(64,12),256,0,stream>>>(qa);

  attn_entmax<<<dim3(2048),512,0,stream>>>(Qbuf, Kbuf, Vt, maskp, ctxb);

  proj_out<<<dim3(128,4),256,0,stream>>>(ctxb, wo, out_b, out);
}

// Round 16
// 180.649 us; speedup vs baseline: 1.2734x; 1.2734x over previous
//
#include <hip/hip_runtime.h>
#include <stdint.h>

typedef _Float16 f16;
typedef __attribute__((ext_vector_type(8))) f16 f16x8;
typedef __attribute__((ext_vector_type(2))) f16 h2;
typedef __attribute__((ext_vector_type(4))) float f32x4;
typedef unsigned short u16;
typedef unsigned int u32;
typedef unsigned char u8;

#define LL 1024
#define DM 512

__device__ __forceinline__ u16 f2h(float f){ return __builtin_bit_cast(u16, (f16)f); }
__device__ __forceinline__ u32 pack2(float a, float b){
  h2 v; v.x = (f16)a; v.y = (f16)b; return __builtin_bit_cast(u32, v);
}
__device__ __forceinline__ f32x4 mfma16h(f16x8 a, f16x8 b, f32x4 c){
  return __builtin_amdgcn_mfma_f32_16x16x32_f16(a, b, c, 0, 0, 0);
}

// ---- DPP 16-lane reductions (row_ror:8/4/2/1), pure VALU, no DS ----
template<int CTRL>
__device__ __forceinline__ float dpp_mov(float x){
  return __builtin_bit_cast(float,
    __builtin_amdgcn_update_dpp(0, __builtin_bit_cast(int, x), CTRL, 0xF, 0xF, true));
}
__device__ __forceinline__ float red_add16(float v){
  v += dpp_mov<0x128>(v);
  v += dpp_mov<0x124>(v);
  v += dpp_mov<0x122>(v);
  v += dpp_mov<0x121>(v);
  return v;
}
__device__ __forceinline__ float red_max16(float v){
  v = fmaxf(v, dpp_mov<0x128>(v));
  v = fmaxf(v, dpp_mov<0x124>(v));
  v = fmaxf(v, dpp_mov<0x122>(v));
  v = fmaxf(v, dpp_mov<0x121>(v));
  return v;
}

// ---------------- fp32 -> f16 convert ----------------
struct CvtArgs {
  const float* src[7];
  u16* dst[7];
  int n4[7];
};

__global__ __launch_bounds__(256) void cvt_kernel(CvtArgs a){
  int seg = blockIdx.y;
  const float4* s = (const float4*)a.src[seg];
  ushort4* d = (ushort4*)a.dst[seg];
  int n4 = a.n4[seg];
  for (int i = blockIdx.x*blockDim.x + threadIdx.x; i < n4; i += gridDim.x*blockDim.x){
    float4 v = s[i];
    ushort4 o;
    o.x = f2h(v.x); o.y = f2h(v.y); o.z = f2h(v.z); o.w = f2h(v.w);
    d[i] = o;
  }
}

// ---------------- fused QKV projection GEMM, 128x128 tile, BK=64 ----------------
// grid (64, 12): which = y>>2 (0=Q,1=K,2=V), nt = y&3.  f16 inputs.
// Staging via global_load_lds width=16; swizzle on GLOBAL source + LDS reads,
// LDS dest linear (rule #21).
struct QkvArgs {
  const u16* A[3];
  const u16* W[3];
  const float* bias[3];
  u16* dst[3];
  float scale[3];
};

__global__ __launch_bounds__(256,2) void proj_qkv(QkvArgs args){
  __shared__ u16 SM[128*128];          // 32 KiB: As(16K)+Bs(16K), reused as stage
  u16* As = SM;
  u16* Bs = SM + 128*64;
  const int tid = threadIdx.x;
  const int w = tid>>6, lane = tid&63;
  const int g = lane>>4, r16 = lane&15;
  const int wr = w>>1, wc = w&1;

  const int which = blockIdx.y>>2, nt = blockIdx.y&3;
  const bool isV = (which==2);
  const u16* A = args.A[which];
  const u16* W = args.W[which];
  const float* bias = args.bias[which];
  u16* dsth = args.dst[which];
  const float scale = args.scale[which];

  const int m0 = blockIdx.x*128, n0 = nt*128;

  f32x4 acc[4][4] = {};

  int rowc[4], slc[4];
  #pragma unroll
  for (int i=0;i<4;++i){
    int c = i*256+tid;
    rowc[i] = c>>3;
    slc[i] = (c&7) ^ ((c>>3)&7);
  }

  const int fswz = r16 & 7;

  for (int k0=0; k0<DM; k0+=64){
    #pragma unroll
    for (int i=0;i<4;++i){
      int c = i*256+tid;
      __builtin_amdgcn_global_load_lds(
        (const __attribute__((address_space(1))) void*)(A + (size_t)(m0+rowc[i])*DM + k0 + slc[i]*8),
        (__attribute__((address_space(3))) void*)(&As[c*8]), 16, 0, 0);
      __builtin_amdgcn_global_load_lds(
        (const __attribute__((address_space(1))) void*)(W + (size_t)(n0+rowc[i])*DM + k0 + slc[i]*8),
        (__attribute__((address_space(3))) void*)(&Bs[c*8]), 16, 0, 0);
    }
    __syncthreads();   // drains vmcnt -> staged LDS ready

    f16x8 af[4][2], bfr[4][2];
    #pragma unroll
    for (int mi=0; mi<4; ++mi){
      int row = wr*64 + mi*16 + r16;
      #pragma unroll
      for (int ks=0; ks<2; ++ks)
        af[mi][ks] = *(const f16x8*)(&As[row*64 + ((ks*4+g)^fswz)*8]);
    }
    #pragma unroll
    for (int ni=0; ni<4; ++ni){
      int row = wc*64 + ni*16 + r16;
      #pragma unroll
      for (int ks=0; ks<2; ++ks)
        bfr[ni][ks] = *(const f16x8*)(&Bs[row*64 + ((ks*4+g)^fswz)*8]);
    }
    if (isV){
      #pragma unroll
      for (int mi=0; mi<4; ++mi)
        #pragma unroll
        for (int ni=0; ni<4; ++ni){
          acc[mi][ni] = mfma16h(af[mi][0], bfr[ni][0], acc[mi][ni]);
          acc[mi][ni] = mfma16h(af[mi][1], bfr[ni][1], acc[mi][ni]);
        }
    } else {
      #pragma unroll
      for (int mi=0; mi<4; ++mi)
        #pragma unroll
        for (int ni=0; ni<4; ++ni){
          acc[mi][ni] = mfma16h(bfr[ni][0], af[mi][0], acc[mi][ni]);
          acc[mi][ni] = mfma16h(bfr[ni][1], af[mi][1], acc[mi][ni]);
        }
    }
    __syncthreads();   // all reads done before next stage overwrites
  }

  // ---- epilogue: stage into chunk-swizzled LDS, then coalesced stores
  if (!isV){
    #pragma unroll
    for (int mi=0; mi<4; ++mi){
      #pragma unroll
      for (int ni=0; ni<4; ++ni){
        f32x4 a = acc[mi][ni];
        int row = wr*64 + mi*16 + r16;
        int c   = wc*16 + ni*4 + g;
        float4 bv = *(const float4*)(bias + n0 + c*4);
        uint2 pk;
        pk.x = pack2((a[0]+bv.x)*scale, (a[1]+bv.y)*scale);
        pk.y = pack2((a[2]+bv.z)*scale, (a[3]+bv.w)*scale);
        *(uint2*)(&SM[row*128 + ((c ^ ((row&7)<<2))<<2)]) = pk;
      }
    }
  } else {
    #pragma unroll
    for (int mi=0; mi<4; ++mi){
      #pragma unroll
      for (int ni=0; ni<4; ++ni){
        f32x4 a = acc[mi][ni];
        int fl = wc*64 + ni*16 + r16;
        int kc = wr*16 + mi*4 + g;
        float bv = bias[n0 + fl];
        uint2 pk;
        pk.x = pack2(a[0]+bv, a[1]+bv);
        pk.y = pack2(a[2]+bv, a[3]+bv);
        *(uint2*)(&SM[fl*128 + ((kc ^ ((fl&7)<<2))<<2)]) = pk;
      }
    }
  }
  __syncthreads();

  #pragma unroll
  for (int rr=0; rr<8; ++rr){
    int row = w*32 + rr*4 + (lane>>4);
    int c0 = (lane&15)*2;
    int cs = c0 ^ ((row&7)<<2);
    uint4 v = *(const uint4*)(&SM[row*128 + (cs<<2)]);
    if (!isV){
      *(uint4*)(dsth + (size_t)(m0+row)*DM + n0 + (c0<<2)) = v;
    } else {
      int n = n0 + row;
      int hh = n>>6, d = n&63, bb = m0>>10;
      *(uint4*)(dsth + (size_t)((bb*8+hh)*64 + d)*1024 + (m0&1023) + (c0<<2)) = v;
    }
  }
}

// ---------------- out-projection GEMM, 64x128 tile, BK=64, grid (128,4) ----------------
__global__ __launch_bounds__(256,2) void proj_out(
    const u16* __restrict__ A, const u16* __restrict__ W,
    const float* __restrict__ bias, float* __restrict__ dstf)
{
  __shared__ u16 As[64*64];
  __shared__ u16 Bs[128*64];
  const int tid = threadIdx.x;
  const int w = tid>>6, lane = tid&63;
  const int g = lane>>4, r16 = lane&15;
  const int m0 = blockIdx.x*64, n0 = blockIdx.y*128;

  f32x4 acc[4][2] = {};

  int rowa[2], slota[2];
  #pragma unroll
  for (int i=0;i<2;++i){ int c = i*256+tid; rowa[i]=c>>3; slota[i]=c&7; }
  int rowb[4], slotb[4];
  #pragma unroll
  for (int i=0;i<4;++i){ int c = i*256+tid; rowb[i]=c>>3; slotb[i]=c&7; }

  uint4 ra[2], rb[4];
  #pragma unroll
  for (int i=0;i<2;++i)
    ra[i] = *(const uint4*)(A + (size_t)(m0+rowa[i])*DM + slota[i]*8);
  #pragma unroll
  for (int i=0;i<4;++i)
    rb[i] = *(const uint4*)(W + (size_t)(n0+rowb[i])*DM + slotb[i]*8);

  const int fswz = r16 & 7;

  for (int k0=0; k0<DM; k0+=64){
    __syncthreads();
    #pragma unroll
    for (int i=0;i<2;++i)
      *(uint4*)(&As[rowa[i]*64 + (slota[i]^(rowa[i]&7))*8]) = ra[i];
    #pragma unroll
    for (int i=0;i<4;++i)
      *(uint4*)(&Bs[rowb[i]*64 + (slotb[i]^(rowb[i]&7))*8]) = rb[i];
    __syncthreads();
    int kn = (k0+64 < DM) ? (k0+64) : 0;
    #pragma unroll
    for (int i=0;i<2;++i)
      ra[i] = *(const uint4*)(A + (size_t)(m0+rowa[i])*DM + kn + slota[i]*8);
    #pragma unroll
    for (int i=0;i<4;++i)
      rb[i] = *(const uint4*)(W + (size_t)(n0+rowb[i])*DM + kn + slotb[i]*8);

    f16x8 af[4][2], bfr[2][2];
    #pragma unroll
    for (int mi=0; mi<4; ++mi){
      int row = mi*16 + r16;
      #pragma unroll
      for (int ks=0; ks<2; ++ks)
        af[mi][ks] = *(const f16x8*)(&As[row*64 + ((ks*4+g)^fswz)*8]);
    }
    #pragma unroll
    for (int ni=0; ni<2; ++ni){
      int row = w*32 + ni*16 + r16;
      #pragma unroll
      for (int ks=0; ks<2; ++ks)
        bfr[ni][ks] = *(const f16x8*)(&Bs[row*64 + ((ks*4+g)^fswz)*8]);
    }
    #pragma unroll
    for (int mi=0; mi<4; ++mi)
      #pragma unroll
      for (int ni=0; ni<2; ++ni){
        acc[mi][ni] = mfma16h(bfr[ni][0], af[mi][0], acc[mi][ni]);
        acc[mi][ni] = mfma16h(bfr[ni][1], af[mi][1], acc[mi][ni]);
      }
  }

  #pragma unroll
  for (int mi=0; mi<4; ++mi){
    #pragma unroll
    for (int ni=0; ni<2; ++ni){
      int m  = m0 + mi*16 + r16;
      int nb = n0 + w*32 + ni*16 + g*4;
      float4 bv = *(const float4*)(bias + nb);
      float4 o;
      o.x = acc[mi][ni][0]+bv.x; o.y = acc[mi][ni][1]+bv.y;
      o.z = acc[mi][ni][2]+bv.z; o.w = acc[mi][ni][3]+bv.w;
      *(float4*)(dstf + (size_t)m*DM + nb) = o;
    }
  }
}

// ---------------- fused attention + entmax-1.5 (r14 structure, session best) ----
// grid 2048, 512 threads (8 waves): bh = ((bid&7)<<3)|((bid>>3)&7), qb = bid>>6.
// 32 q-rows/block, S[32][1024] f16 = 64 KiB (2 blocks/CU).
// Newton 5 iters + finalize (renorm absorbs residual tau). setprio on C MFMAs.
// Falsified levers (keep for the record): occupancy (r12), VALU-count beyond
// Newton-5 (r10), phase mixing (r13), 2-deep prefetch (r11), deep prefetch
// (r15: VGPR spill, WRITE_SIZE 8->258MB). This is the measured optimum.
// Swizzle: (row,k) at u16 off row*1024 + (k ^ (cc<<3)), cc = ((k>>6)&7) ^ (row&7).
__global__ __launch_bounds__(512,4) void attn_entmax(
    const u16* __restrict__ Qf, const u16* __restrict__ Kf,
    const u16* __restrict__ Vt, const u8* __restrict__ mask,
    u16* __restrict__ ctx)
{
  __shared__ u16 S[32*1024];   // 64 KiB

  const int tid = threadIdx.x, w = tid>>6, lane = tid&63;
  const int g = lane>>4, r16 = lane&15;
  const int bid = blockIdx.x;
  const int bh = ((bid&7)<<3) | ((bid>>3)&7);
  const int qb = bid>>6;
  const int b = bh>>3, h = bh&7;
  const int q0 = qb*32;
  const u16* Qb = Qf + ((size_t)(b*LL + q0))*DM + h*64;
  const u16* Kb = Kf + ((size_t)(b*LL))*DM + h*64;

  // ---- Phase A: S^T = K Q^T (scale folded into Q); wave w: keys [w*128,+128)
  // K pair-loads double-buffered 2 kt ahead.
  f16x8 qf[2][2];
  #pragma unroll
  for (int qi=0;qi<2;++qi){
    qf[qi][0] = *(const f16x8*)(Qb + (size_t)(qi*16 + r16)*DM + g*8);
    qf[qi][1] = *(const f16x8*)(Qb + (size_t)(qi*16 + r16)*DM + 32 + g*8);
  }
  {
    f16x8 kc[2][2], kn[2][2];
    #pragma unroll
    for (int j=0;j<2;++j){
      const u16* kp = Kb + (size_t)(w*128 + j*16 + r16)*DM + g*8;
      kc[j][0] = *(const f16x8*)(kp);
      kc[j][1] = *(const f16x8*)(kp + 32);
    }
    #pragma unroll
    for (int grp=0; grp<4; ++grp){
      #pragma unroll
      for (int j=0;j<2;++j){
        if (grp < 3){
          const u16* kp = Kb + (size_t)(w*128 + (grp*2+2+j)*16 + r16)*DM + g*8;
          kn[j][0] = *(const f16x8*)(kp);
          kn[j][1] = *(const f16x8*)(kp + 32);
        }
      }
      #pragma unroll
      for (int j=0;j<2;++j){
        int kt = grp*2 + j;
        int krow = w*128 + kt*16;
        int kb = krow + g*4;
        u32 m4 = *(const u32*)(mask + b*LL + kb);
        #pragma unroll
        for (int qi=0; qi<2; ++qi){
          f32x4 acc = {};
          acc = mfma16h(kc[j][0], qf[qi][0], acc);   // reg-dim: key, col: q=r16
          acc = mfma16h(kc[j][1], qf[qi][1], acc);
          float v0 = (m4 & 0xFFu)       ? -30000.f : acc[0];
          float v1 = (m4 & 0xFF00u)     ? -30000.f : acc[1];
          float v2 = (m4 & 0xFF0000u)   ? -30000.f : acc[2];
          float v3 = (m4 & 0xFF000000u) ? -30000.f : acc[3];
          int row = qi*16 + r16;
          int cc = ((kb>>6)&7) ^ (row&7);
          uint2 pk; pk.x = pack2(v0,v1); pk.y = pack2(v2,v3);
          *(uint2*)(&S[row*LL + (kb ^ (cc<<3))]) = pk;
        }
      }
      #pragma unroll
      for (int j=0;j<2;++j){ kc[j][0]=kn[j][0]; kc[j][1]=kn[j][1]; }
    }
  }
  __syncthreads();

  // ---- Phase B: entmax-1.5; row = w*4+g (4 rows/wave in parallel),
  // lane r16 holds 64 contiguous keys as 32 h2; all-DPP reduces; 5 Newton iters.
  {
    const int r = w*4 + g;
    const int ccb = (r16 ^ r) & 7;
    h2 zp[32];
    #pragma unroll
    for (int c=0;c<8;++c){
      uint4 v = *(const uint4*)(&S[r*LL + ((r16*64 + c*8) ^ (ccb<<3))]);
      zp[c*4+0] = __builtin_bit_cast(h2, v.x);
      zp[c*4+1] = __builtin_bit_cast(h2, v.y);
      zp[c*4+2] = __builtin_bit_cast(h2, v.z);
      zp[c*4+3] = __builtin_bit_cast(h2, v.w);
    }
    h2 m2 = zp[0];
    #pragma unroll
    for (int t=1;t<32;++t) m2 = __builtin_elementwise_max(m2, zp[t]);
    float mx = red_max16(fmaxf((float)m2.x, (float)m2.y));

    const h2 zero2 = (h2)(f16)0;
    float lo = mx - 1.0f, hi = mx, tau = mx - 0.5f;
    #pragma unroll 1
    for (int it=0; it<5; ++it){
      f16 th = (f16)tau;
      h2 t2; t2.x = th; t2.y = th;
      h2 s1a = zero2, s1b = zero2, s2a = zero2, s2b = zero2;
      #pragma unroll
      for (int t=0;t<32;t+=2){
        h2 d0 = __builtin_elementwise_max(zp[t]   - t2, zero2);
        h2 d1 = __builtin_elementwise_max(zp[t+1] - t2, zero2);
        s1a = s1a + d0;        s1b = s1b + d1;
        s2a = s2a + d0*d0;     s2b = s2b + d1*d1;
      }
      h2 s1h = s1a + s1b, s2h = s2a + s2b;
      float s1 = red_add16((float)s1h.x + (float)s1h.y);
      float s2 = red_add16((float)s2h.x + (float)s2h.y);
      if (s2 >= 1.0f) lo = tau; else hi = tau;
      float tn = tau + (s2 - 1.0f)/(2.0f*s1);
      tau = (tn >= lo && tn < hi) ? tn : 0.5f*(lo+hi);
    }

    {
      f16 th = (f16)tau;
      h2 t2; t2.x = th; t2.y = th;
      h2 psa = zero2, psb = zero2;
      #pragma unroll
      for (int t=0;t<32;t+=2){
        h2 d0 = __builtin_elementwise_max(zp[t]   - t2, zero2);
        h2 d1 = __builtin_elementwise_max(zp[t+1] - t2, zero2);
        h2 p0 = d0*d0, p1 = d1*d1;
        zp[t] = p0; zp[t+1] = p1;
        psa = psa + p0; psb = psb + p1;
      }
      h2 ps2 = psa + psb;
      float ps = red_add16((float)ps2.x + (float)ps2.y);
      f16 iv = (f16)(1.0f/ps);
      h2 i2; i2.x = iv; i2.y = iv;
      #pragma unroll
      for (int c=0;c<8;++c){
        uint4 v;
        v.x = __builtin_bit_cast(u32, (h2)(zp[c*4+0]*i2));
        v.y = __builtin_bit_cast(u32, (h2)(zp[c*4+1]*i2));
        v.z = __builtin_bit_cast(u32, (h2)(zp[c*4+2]*i2));
        v.w = __builtin_bit_cast(u32, (h2)(zp[c*4+3]*i2));
        *(uint4*)(&S[r*LL + ((r16*64 + c*8) ^ (ccb<<3))]) = v;  // same slots read
      }
    }
  }
  __syncthreads();

  // ---- Phase C: ctx = P @ V ; wave w -> q-tile (w>>2), d-tile (w&3);
  // P(LDS) + V(L2) loads double-buffered 4 kt ahead; setprio around MFMAs.
  const int qi = w>>2, di = w&3;
  const u16* vrow = Vt + (size_t)(bh*64 + di*16 + r16)*LL;
  const int prow = qi*16 + r16;
  f32x4 o0 = {}, o1 = {};
  {
    f16x8 pc[4], vc[4], pn[4], vn[4];
    #pragma unroll
    for (int j=0;j<4;++j){
      int k = j*32 + g*8;
      int cc = ((k>>6)&7) ^ (prow&7);
      pc[j] = *(const f16x8*)(&S[prow*LL + (k ^ (cc<<3))]);
      vc[j] = *(const f16x8*)(vrow + k);
    }
    #pragma unroll
    for (int grp=0; grp<8; ++grp){
      #pragma unroll
      for (int j=0;j<4;++j){
        if (grp < 7){
          int k = (grp*4+4+j)*32 + g*8;
          int cc = ((k>>6)&7) ^ (prow&7);
          pn[j] = *(const f16x8*)(&S[prow*LL + (k ^ (cc<<3))]);
          vn[j] = *(const f16x8*)(vrow + k);
        }
      }
      __builtin_amdgcn_s_setprio(1);
      #pragma unroll
      for (int j=0;j<4;++j){
        if (j & 1) o1 = mfma16h(pc[j], vc[j], o1);
        else       o0 = mfma16h(pc[j], vc[j], o0);
      }
      __builtin_amdgcn_s_setprio(0);
      #pragma unroll
      for (int j=0;j<4;++j){ pc[j]=pn[j]; vc[j]=vn[j]; }
    }
  }
  #pragma unroll
  for (int r=0;r<4;++r){
    int q = q0 + qi*16 + g*4 + r;
    ctx[(size_t)(b*LL + q)*DM + h*64 + di*16 + r16] = f2h(o0[r] + o1[r]);
  }
}

// ---------------- launch ----------------
extern "C" void kernel_launch(void* const* d_in, const int* in_sizes, int n_in,
                              void* d_out, int out_size, void* d_ws, size_t ws_size,
                              hipStream_t stream) {
  const float* query = (const float*)d_in[0];
  const float* key   = (const float*)d_in[1];
  const float* value = (const float*)d_in[2];
  const u8*    maskp = (const u8*)d_in[3];
  const float* q_w = (const float*)d_in[4];
  const float* q_b = (const float*)d_in[5];
  const float* k_w = (const float*)d_in[6];
  const float* k_b = (const float*)d_in[7];
  const float* v_w = (const float*)d_in[8];
  const float* v_b = (const float*)d_in[9];
  const float* out_w = (const float*)d_in[10];
  const float* out_b = (const float*)d_in[11];
  float* out = (float*)d_out;

  u16* qx = (u16*)d_ws;                 // 4M f16 elems each
  u16* kx = qx + 4194304;
  u16* vx = kx + 4194304;
  u16* wq = vx + 4194304;               // 256K elems each
  u16* wk = wq + 262144;
  u16* wv = wk + 262144;
  u16* wo = wv + 262144;
  u16* Qbuf = wo + 262144;              // 4M elems each
  u16* Kbuf = Qbuf + 4194304;
  u16* Vt   = Kbuf + 4194304;
  u16* ctxb = Vt + 4194304;

  CvtArgs ca;
  ca.src[0]=query; ca.dst[0]=qx; ca.n4[0]=8*LL*DM/4;
  ca.src[1]=key;   ca.dst[1]=kx; ca.n4[1]=8*LL*DM/4;
  ca.src[2]=value; ca.dst[2]=vx; ca.n4[2]=8*LL*DM/4;
  ca.src[3]=q_w;   ca.dst[3]=wq; ca.n4[3]=DM*DM/4;
  ca.src[4]=k_w;   ca.dst[4]=wk; ca.n4[4]=DM*DM/4;
  ca.src[5]=v_w;   ca.dst[5]=wv; ca.n4[5]=DM*DM/4;
  ca.src[6]=out_w; ca.dst[6]=wo; ca.n4[6]=DM*DM/4;
  cvt_kernel<<<dim3(512,7),256,0,stream>>>(ca);

  QkvArgs qa;
  qa.A[0]=qx; qa.A[1]=kx; qa.A[2]=vx;
  qa.W[0]=wq; qa.W[1]=wk; qa.W[2]=wv;
  qa.bias[0]=q_b; qa.bias[1]=k_b; qa.bias[2]=v_b;
  qa.dst[0]=Qbuf; qa.dst[1]=Kbuf; qa.dst[2]=Vt;
  qa.scale[0]=0.0625f; qa.scale[1]=1.0f; qa.scale[2]=1.0f; // 1/8 (dh^-0.5) * 1/2 on Q

  proj_qkv<<<dim3(64,12),256,0,stream>>>(qa);

  attn_entmax<<<dim3(2048),512,0,stream>>>(Qbuf, Kbuf, Vt, maskp, ctxb);

  proj_out<<<dim3(128,4),256,0,stream>>>(ctxb, wo, out_b, out);
}

// Round 17
// 169.662 us; speedup vs baseline: 1.3559x; 1.0648x over previous
//
#include <hip/hip_runtime.h>
#include <stdint.h>

typedef _Float16 f16;
typedef __attribute__((ext_vector_type(8))) f16 f16x8;
typedef __attribute__((ext_vector_type(2))) f16 h2;
typedef __attribute__((ext_vector_type(4))) float f32x4;
typedef unsigned short u16;
typedef unsigned int u32;
typedef unsigned char u8;

#define LL 1024
#define DM 512

__device__ __forceinline__ u16 f2h(float f){ return __builtin_bit_cast(u16, (f16)f); }
__device__ __forceinline__ u32 pack2(float a, float b){
  h2 v; v.x = (f16)a; v.y = (f16)b; return __builtin_bit_cast(u32, v);
}
__device__ __forceinline__ f32x4 mfma16h(f16x8 a, f16x8 b, f32x4 c){
  return __builtin_amdgcn_mfma_f32_16x16x32_f16(a, b, c, 0, 0, 0);
}

// ---- DPP 16-lane reductions (row_ror:8/4/2/1), pure VALU, no DS ----
template<int CTRL>
__device__ __forceinline__ float dpp_mov(float x){
  return __builtin_bit_cast(float,
    __builtin_amdgcn_update_dpp(0, __builtin_bit_cast(int, x), CTRL, 0xF, 0xF, true));
}
__device__ __forceinline__ float red_add16(float v){
  v += dpp_mov<0x128>(v);
  v += dpp_mov<0x124>(v);
  v += dpp_mov<0x122>(v);
  v += dpp_mov<0x121>(v);
  return v;
}
__device__ __forceinline__ float red_max16(float v){
  v = fmaxf(v, dpp_mov<0x128>(v));
  v = fmaxf(v, dpp_mov<0x124>(v));
  v = fmaxf(v, dpp_mov<0x122>(v));
  v = fmaxf(v, dpp_mov<0x121>(v));
  return v;
}

// ---------------- fp32 -> f16 convert ----------------
struct CvtArgs {
  const float* src[7];
  u16* dst[7];
  int n4[7];
};

__global__ __launch_bounds__(256) void cvt_kernel(CvtArgs a){
  int seg = blockIdx.y;
  const float4* s = (const float4*)a.src[seg];
  ushort4* d = (ushort4*)a.dst[seg];
  int n4 = a.n4[seg];
  for (int i = blockIdx.x*blockDim.x + threadIdx.x; i < n4; i += gridDim.x*blockDim.x){
    float4 v = s[i];
    ushort4 o;
    o.x = f2h(v.x); o.y = f2h(v.y); o.z = f2h(v.z); o.w = f2h(v.w);
    d[i] = o;
  }
}

// ---------------- fused QKV projection GEMM, 128x128 tile, BK=64 ----------------
// grid (64, 12): which = y>>2 (0=Q,1=K,2=V), nt = y&3.  f16 inputs.
// Staging via global_load_lds width=16; swizzle on GLOBAL source + LDS reads,
// LDS dest linear (rule #21).
struct QkvArgs {
  const u16* A[3];
  const u16* W[3];
  const float* bias[3];
  u16* dst[3];
  float scale[3];
};

__global__ __launch_bounds__(256,2) void proj_qkv(QkvArgs args){
  __shared__ u16 SM[128*128];          // 32 KiB: As(16K)+Bs(16K), reused as stage
  u16* As = SM;
  u16* Bs = SM + 128*64;
  const int tid = threadIdx.x;
  const int w = tid>>6, lane = tid&63;
  const int g = lane>>4, r16 = lane&15;
  const int wr = w>>1, wc = w&1;

  const int which = blockIdx.y>>2, nt = blockIdx.y&3;
  const bool isV = (which==2);
  const u16* A = args.A[which];
  const u16* W = args.W[which];
  const float* bias = args.bias[which];
  u16* dsth = args.dst[which];
  const float scale = args.scale[which];

  const int m0 = blockIdx.x*128, n0 = nt*128;

  f32x4 acc[4][4] = {};

  int rowc[4], slc[4];
  #pragma unroll
  for (int i=0;i<4;++i){
    int c = i*256+tid;
    rowc[i] = c>>3;
    slc[i] = (c&7) ^ ((c>>3)&7);
  }

  const int fswz = r16 & 7;

  for (int k0=0; k0<DM; k0+=64){
    #pragma unroll
    for (int i=0;i<4;++i){
      int c = i*256+tid;
      __builtin_amdgcn_global_load_lds(
        (const __attribute__((address_space(1))) void*)(A + (size_t)(m0+rowc[i])*DM + k0 + slc[i]*8),
        (__attribute__((address_space(3))) void*)(&As[c*8]), 16, 0, 0);
      __builtin_amdgcn_global_load_lds(
        (const __attribute__((address_space(1))) void*)(W + (size_t)(n0+rowc[i])*DM + k0 + slc[i]*8),
        (__attribute__((address_space(3))) void*)(&Bs[c*8]), 16, 0, 0);
    }
    __syncthreads();   // drains vmcnt -> staged LDS ready

    f16x8 af[4][2], bfr[4][2];
    #pragma unroll
    for (int mi=0; mi<4; ++mi){
      int row = wr*64 + mi*16 + r16;
      #pragma unroll
      for (int ks=0; ks<2; ++ks)
        af[mi][ks] = *(const f16x8*)(&As[row*64 + ((ks*4+g)^fswz)*8]);
    }
    #pragma unroll
    for (int ni=0; ni<4; ++ni){
      int row = wc*64 + ni*16 + r16;
      #pragma unroll
      for (int ks=0; ks<2; ++ks)
        bfr[ni][ks] = *(const f16x8*)(&Bs[row*64 + ((ks*4+g)^fswz)*8]);
    }
    if (isV){
      #pragma unroll
      for (int mi=0; mi<4; ++mi)
        #pragma unroll
        for (int ni=0; ni<4; ++ni){
          acc[mi][ni] = mfma16h(af[mi][0], bfr[ni][0], acc[mi][ni]);
          acc[mi][ni] = mfma16h(af[mi][1], bfr[ni][1], acc[mi][ni]);
        }
    } else {
      #pragma unroll
      for (int mi=0; mi<4; ++mi)
        #pragma unroll
        for (int ni=0; ni<4; ++ni){
          acc[mi][ni] = mfma16h(bfr[ni][0], af[mi][0], acc[mi][ni]);
          acc[mi][ni] = mfma16h(bfr[ni][1], af[mi][1], acc[mi][ni]);
        }
    }
    __syncthreads();   // all reads done before next stage overwrites
  }

  // ---- epilogue: stage into chunk-swizzled LDS, then coalesced stores
  if (!isV){
    #pragma unroll
    for (int mi=0; mi<4; ++mi){
      #pragma unroll
      for (int ni=0; ni<4; ++ni){
        f32x4 a = acc[mi][ni];
        int row = wr*64 + mi*16 + r16;
        int c   = wc*16 + ni*4 + g;
        float4 bv = *(const float4*)(bias + n0 + c*4);
        uint2 pk;
        pk.x = pack2((a[0]+bv.x)*scale, (a[1]+bv.y)*scale);
        pk.y = pack2((a[2]+bv.z)*scale, (a[3]+bv.w)*scale);
        *(uint2*)(&SM[row*128 + ((c ^ ((row&7)<<2))<<2)]) = pk;
      }
    }
  } else {
    #pragma unroll
    for (int mi=0; mi<4; ++mi){
      #pragma unroll
      for (int ni=0; ni<4; ++ni){
        f32x4 a = acc[mi][ni];
        int fl = wc*64 + ni*16 + r16;
        int kc = wr*16 + mi*4 + g;
        float bv = bias[n0 + fl];
        uint2 pk;
        pk.x = pack2(a[0]+bv, a[1]+bv);
        pk.y = pack2(a[2]+bv, a[3]+bv);
        *(uint2*)(&SM[fl*128 + ((kc ^ ((fl&7)<<2))<<2)]) = pk;
      }
    }
  }
  __syncthreads();

  #pragma unroll
  for (int rr=0; rr<8; ++rr){
    int row = w*32 + rr*4 + (lane>>4);
    int c0 = (lane&15)*2;
    int cs = c0 ^ ((row&7)<<2);
    uint4 v = *(const uint4*)(&SM[row*128 + (cs<<2)]);
    if (!isV){
      *(uint4*)(dsth + (size_t)(m0+row)*DM + n0 + (c0<<2)) = v;
    } else {
      int n = n0 + row;
      int hh = n>>6, d = n&63, bb = m0>>10;
      *(uint4*)(dsth + (size_t)((bb*8+hh)*64 + d)*1024 + (m0&1023) + (c0<<2)) = v;
    }
  }
}

// ---------------- out-projection GEMM, 64x128 tile, BK=64, grid (128,4) ----------------
__global__ __launch_bounds__(256,2) void proj_out(
    const u16* __restrict__ A, const u16* __restrict__ W,
    const float* __restrict__ bias, float* __restrict__ dstf)
{
  __shared__ u16 As[64*64];
  __shared__ u16 Bs[128*64];
  const int tid = threadIdx.x;
  const int w = tid>>6, lane = tid&63;
  const int g = lane>>4, r16 = lane&15;
  const int m0 = blockIdx.x*64, n0 = blockIdx.y*128;

  f32x4 acc[4][2] = {};

  int rowa[2], slota[2];
  #pragma unroll
  for (int i=0;i<2;++i){ int c = i*256+tid; rowa[i]=c>>3; slota[i]=c&7; }
  int rowb[4], slotb[4];
  #pragma unroll
  for (int i=0;i<4;++i){ int c = i*256+tid; rowb[i]=c>>3; slotb[i]=c&7; }

  uint4 ra[2], rb[4];
  #pragma unroll
  for (int i=0;i<2;++i)
    ra[i] = *(const uint4*)(A + (size_t)(m0+rowa[i])*DM + slota[i]*8);
  #pragma unroll
  for (int i=0;i<4;++i)
    rb[i] = *(const uint4*)(W + (size_t)(n0+rowb[i])*DM + slotb[i]*8);

  const int fswz = r16 & 7;

  for (int k0=0; k0<DM; k0+=64){
    __syncthreads();
    #pragma unroll
    for (int i=0;i<2;++i)
      *(uint4*)(&As[rowa[i]*64 + (slota[i]^(rowa[i]&7))*8]) = ra[i];
    #pragma unroll
    for (int i=0;i<4;++i)
      *(uint4*)(&Bs[rowb[i]*64 + (slotb[i]^(rowb[i]&7))*8]) = rb[i];
    __syncthreads();
    int kn = (k0+64 < DM) ? (k0+64) : 0;
    #pragma unroll
    for (int i=0;i<2;++i)
      ra[i] = *(const uint4*)(A + (size_t)(m0+rowa[i])*DM + kn + slota[i]*8);
    #pragma unroll
    for (int i=0;i<4;++i)
      rb[i] = *(const uint4*)(W + (size_t)(n0+rowb[i])*DM + kn + slotb[i]*8);

    f16x8 af[4][2], bfr[2][2];
    #pragma unroll
    for (int mi=0; mi<4; ++mi){
      int row = mi*16 + r16;
      #pragma unroll
      for (int ks=0; ks<2; ++ks)
        af[mi][ks] = *(const f16x8*)(&As[row*64 + ((ks*4+g)^fswz)*8]);
    }
    #pragma unroll
    for (int ni=0; ni<2; ++ni){
      int row = w*32 + ni*16 + r16;
      #pragma unroll
      for (int ks=0; ks<2; ++ks)
        bfr[ni][ks] = *(const f16x8*)(&Bs[row*64 + ((ks*4+g)^fswz)*8]);
    }
    #pragma unroll
    for (int mi=0; mi<4; ++mi)
      #pragma unroll
      for (int ni=0; ni<2; ++ni){
        acc[mi][ni] = mfma16h(bfr[ni][0], af[mi][0], acc[mi][ni]);
        acc[mi][ni] = mfma16h(bfr[ni][1], af[mi][1], acc[mi][ni]);
      }
  }

  #pragma unroll
  for (int mi=0; mi<4; ++mi){
    #pragma unroll
    for (int ni=0; ni<2; ++ni){
      int m  = m0 + mi*16 + r16;
      int nb = n0 + w*32 + ni*16 + g*4;
      float4 bv = *(const float4*)(bias + nb);
      float4 o;
      o.x = acc[mi][ni][0]+bv.x; o.y = acc[mi][ni][1]+bv.y;
      o.z = acc[mi][ni][2]+bv.z; o.w = acc[mi][ni][3]+bv.w;
      *(float4*)(dstf + (size_t)m*DM + nb) = o;
    }
  }
}

// ---------------- fused attention + entmax-1.5 (r14 + pinned A-burst) ----------
// grid 2048, 512 threads (8 waves): bh = ((bid&7)<<3)|((bid>>3)&7), qb = bid>>6.
// 32 q-rows/block, S[32][1024] f16 = 64 KiB (2 blocks/CU).
// Phase A: full 16-load K burst + sched_barrier(0) pin — tests whether r11's
// prefetch null was compiler load-sinking (VGPR stayed 56 with 64 regs of
// declared buffers = loads were serialized). A-burst alone ~102 VGPR < 128 cap
// (r15's spill came from stacking C's 96-reg buffer on top).
// Phase C: r14's 4-deep dbuf. Newton 5 iters + finalize. setprio on C MFMAs.
// Swizzle: (row,k) at u16 off row*1024 + (k^(cc<<3)), cc = ((k>>6)&7) ^ (row&7).
__global__ __launch_bounds__(512,4) void attn_entmax(
    const u16* __restrict__ Qf, const u16* __restrict__ Kf,
    const u16* __restrict__ Vt, const u8* __restrict__ mask,
    u16* __restrict__ ctx)
{
  __shared__ u16 S[32*1024];   // 64 KiB

  const int tid = threadIdx.x, w = tid>>6, lane = tid&63;
  const int g = lane>>4, r16 = lane&15;
  const int bid = blockIdx.x;
  const int bh = ((bid&7)<<3) | ((bid>>3)&7);
  const int qb = bid>>6;
  const int b = bh>>3, h = bh&7;
  const int q0 = qb*32;
  const u16* Qb = Qf + ((size_t)(b*LL + q0))*DM + h*64;
  const u16* Kb = Kf + ((size_t)(b*LL))*DM + h*64;

  // ---- Phase A: S^T = K Q^T (scale folded into Q); wave w: keys [w*128,+128)
  f16x8 qf[2][2];
  #pragma unroll
  for (int qi=0;qi<2;++qi){
    qf[qi][0] = *(const f16x8*)(Qb + (size_t)(qi*16 + r16)*DM + g*8);
    qf[qi][1] = *(const f16x8*)(Qb + (size_t)(qi*16 + r16)*DM + 32 + g*8);
  }
  {
    f16x8 kr0[8], kr1[8];
    u32 m4a[8];
    #pragma unroll
    for (int kt=0;kt<8;++kt){
      const u16* kp = Kb + (size_t)(w*128 + kt*16 + r16)*DM + g*8;
      kr0[kt] = *(const f16x8*)(kp);
      kr1[kt] = *(const f16x8*)(kp + 32);
      m4a[kt] = *(const u32*)(mask + b*LL + w*128 + kt*16 + g*4);
    }
    __builtin_amdgcn_sched_barrier(0);   // pin: all 16 loads issued before use
    #pragma unroll
    for (int kt=0;kt<8;++kt){
      int kb = w*128 + kt*16 + g*4;
      u32 m4 = m4a[kt];
      #pragma unroll
      for (int qi=0; qi<2; ++qi){
        f32x4 acc = {};
        acc = mfma16h(kr0[kt], qf[qi][0], acc);   // reg-dim: key, col: q=r16
        acc = mfma16h(kr1[kt], qf[qi][1], acc);
        float v0 = (m4 & 0xFFu)       ? -30000.f : acc[0];
        float v1 = (m4 & 0xFF00u)     ? -30000.f : acc[1];
        float v2 = (m4 & 0xFF0000u)   ? -30000.f : acc[2];
        float v3 = (m4 & 0xFF000000u) ? -30000.f : acc[3];
        int row = qi*16 + r16;
        int cc = ((kb>>6)&7) ^ (row&7);
        uint2 pk; pk.x = pack2(v0,v1); pk.y = pack2(v2,v3);
        *(uint2*)(&S[row*LL + (kb ^ (cc<<3))]) = pk;
      }
    }
  }
  __syncthreads();

  // ---- Phase B: entmax-1.5; row = w*4+g (4 rows/wave in parallel),
  // lane r16 holds 64 contiguous keys as 32 h2; all-DPP reduces; 5 Newton iters.
  {
    const int r = w*4 + g;
    const int ccb = (r16 ^ r) & 7;
    h2 zp[32];
    #pragma unroll
    for (int c=0;c<8;++c){
      uint4 v = *(const uint4*)(&S[r*LL + ((r16*64 + c*8) ^ (ccb<<3))]);
      zp[c*4+0] = __builtin_bit_cast(h2, v.x);
      zp[c*4+1] = __builtin_bit_cast(h2, v.y);
      zp[c*4+2] = __builtin_bit_cast(h2, v.z);
      zp[c*4+3] = __builtin_bit_cast(h2, v.w);
    }
    h2 m2 = zp[0];
    #pragma unroll
    for (int t=1;t<32;++t) m2 = __builtin_elementwise_max(m2, zp[t]);
    float mx = red_max16(fmaxf((float)m2.x, (float)m2.y));

    const h2 zero2 = (h2)(f16)0;
    float lo = mx - 1.0f, hi = mx, tau = mx - 0.5f;
    #pragma unroll 1
    for (int it=0; it<5; ++it){
      f16 th = (f16)tau;
      h2 t2; t2.x = th; t2.y = th;
      h2 s1a = zero2, s1b = zero2, s2a = zero2, s2b = zero2;
      #pragma unroll
      for (int t=0;t<32;t+=2){
        h2 d0 = __builtin_elementwise_max(zp[t]   - t2, zero2);
        h2 d1 = __builtin_elementwise_max(zp[t+1] - t2, zero2);
        s1a = s1a + d0;        s1b = s1b + d1;
        s2a = s2a + d0*d0;     s2b = s2b + d1*d1;
      }
      h2 s1h = s1a + s1b, s2h = s2a + s2b;
      float s1 = red_add16((float)s1h.x + (float)s1h.y);
      float s2 = red_add16((float)s2h.x + (float)s2h.y);
      if (s2 >= 1.0f) lo = tau; else hi = tau;
      float tn = tau + (s2 - 1.0f)/(2.0f*s1);
      tau = (tn >= lo && tn < hi) ? tn : 0.5f*(lo+hi);
    }

    {
      f16 th = (f16)tau;
      h2 t2; t2.x = th; t2.y = th;
      h2 psa = zero2, psb = zero2;
      #pragma unroll
      for (int t=0;t<32;t+=2){
        h2 d0 = __builtin_elementwise_max(zp[t]   - t2, zero2);
        h2 d1 = __builtin_elementwise_max(zp[t+1] - t2, zero2);
        h2 p0 = d0*d0, p1 = d1*d1;
        zp[t] = p0; zp[t+1] = p1;
        psa = psa + p0; psb = psb + p1;
      }
      h2 ps2 = psa + psb;
      float ps = red_add16((float)ps2.x + (float)ps2.y);
      f16 iv = (f16)(1.0f/ps);
      h2 i2; i2.x = iv; i2.y = iv;
      #pragma unroll
      for (int c=0;c<8;++c){
        uint4 v;
        v.x = __builtin_bit_cast(u32, (h2)(zp[c*4+0]*i2));
        v.y = __builtin_bit_cast(u32, (h2)(zp[c*4+1]*i2));
        v.z = __builtin_bit_cast(u32, (h2)(zp[c*4+2]*i2));
        v.w = __builtin_bit_cast(u32, (h2)(zp[c*4+3]*i2));
        *(uint4*)(&S[r*LL + ((r16*64 + c*8) ^ (ccb<<3))]) = v;  // same slots read
      }
    }
  }
  __syncthreads();

  // ---- Phase C: ctx = P @ V ; wave w -> q-tile (w>>2), d-tile (w&3);
  // P(LDS) + V(L2) loads double-buffered 4 kt ahead; setprio around MFMAs.
  const int qi = w>>2, di = w&3;
  const u16* vrow = Vt + (size_t)(bh*64 + di*16 + r16)*LL;
  const int prow = qi*16 + r16;
  f32x4 o0 = {}, o1 = {};
  {
    f16x8 pc[4], vc[4], pn[4], vn[4];
    #pragma unroll
    for (int j=0;j<4;++j){
      int k = j*32 + g*8;
      int cc = ((k>>6)&7) ^ (prow&7);
      pc[j] = *(const f16x8*)(&S[prow*LL + (k ^ (cc<<3))]);
      vc[j] = *(const f16x8*)(vrow + k);
    }
    #pragma unroll
    for (int grp=0; grp<8; ++grp){
      #pragma unroll
      for (int j=0;j<4;++j){
        if (grp < 7){
          int k = (grp*4+4+j)*32 + g*8;
          int cc = ((k>>6)&7) ^ (prow&7);
          pn[j] = *(const f16x8*)(&S[prow*LL + (k ^ (cc<<3))]);
          vn[j] = *(const f16x8*)(vrow + k);
        }
      }
      __builtin_amdgcn_s_setprio(1);
      #pragma unroll
      for (int j=0;j<4;++j){
        if (j & 1) o1 = mfma16h(pc[j], vc[j], o1);
        else       o0 = mfma16h(pc[j], vc[j], o0);
      }
      __builtin_amdgcn_s_setprio(0);
      #pragma unroll
      for (int j=0;j<4;++j){ pc[j]=pn[j]; vc[j]=vn[j]; }
    }
  }
  #pragma unroll
  for (int r=0;r<4;++r){
    int q = q0 + qi*16 + g*4 + r;
    ctx[(size_t)(b*LL + q)*DM + h*64 + di*16 + r16] = f2h(o0[r] + o1[r]);
  }
}

// ---------------- launch ----------------
extern "C" void kernel_launch(void* const* d_in, const int* in_sizes, int n_in,
                              void* d_out, int out_size, void* d_ws, size_t ws_size,
                              hipStream_t stream) {
  const float* query = (const float*)d_in[0];
  const float* key   = (const float*)d_in[1];
  const float* value = (const float*)d_in[2];
  const u8*    maskp = (const u8*)d_in[3];
  const float* q_w = (const float*)d_in[4];
  const float* q_b = (const float*)d_in[5];
  const float* k_w = (const float*)d_in[6];
  const float* k_b = (const float*)d_in[7];
  const float* v_w = (const float*)d_in[8];
  const float* v_b = (const float*)d_in[9];
  const float* out_w = (const float*)d_in[10];
  const float* out_b = (const float*)d_in[11];
  float* out = (float*)d_out;

  u16* qx = (u16*)d_ws;                 // 4M f16 elems each
  u16* kx = qx + 4194304;
  u16* vx = kx + 4194304;
  u16* wq = vx + 4194304;               // 256K elems each
  u16* wk = wq + 262144;
  u16* wv = wk + 262144;
  u16* wo = wv + 262144;
  u16* Qbuf = wo + 262144;              // 4M elems each
  u16* Kbuf = Qbuf + 4194304;
  u16* Vt   = Kbuf + 4194304;
  u16* ctxb = Vt + 4194304;

  CvtArgs ca;
  ca.src[0]=query; ca.dst[0]=qx; ca.n4[0]=8*LL*DM/4;
  ca.src[1]=key;   ca.dst[1]=kx; ca.n4[1]=8*LL*DM/4;
  ca.src[2]=value; ca.dst[2]=vx; ca.n4[2]=8*LL*DM/4;
  ca.src[3]=q_w;   ca.dst[3]=wq; ca.n4[3]=DM*DM/4;
  ca.src[4]=k_w;   ca.dst[4]=wk; ca.n4[4]=DM*DM/4;
  ca.src[5]=v_w;   ca.dst[5]=wv; ca.n4[5]=DM*DM/4;
  ca.src[6]=out_w; ca.dst[6]=wo; ca.n4[6]=DM*DM/4;
  cvt_kernel<<<dim3(512,7),256,0,stream>>>(ca);

  QkvArgs qa;
  qa.A[0]=qx; qa.A[1]=kx; qa.A[2]=vx;
  qa.W[0]=wq; qa.W[1]=wk; qa.W[2]=wv;
  qa.bias[0]=q_b; qa.bias[1]=k_b; qa.bias[2]=v_b;
  qa.dst[0]=Qbuf; qa.dst[1]=Kbuf; qa.dst[2]=Vt;
  qa.scale[0]=0.0625f; qa.scale[1]=1.0f; qa.scale[2]=1.0f; // 1/8 (dh^-0.5) * 1/2 on Q

  proj_qkv<<<dim3(64,12),256,0,stream>>>(qa);

  attn_entmax<<<dim3(2048),512,0,stream>>>(Qbuf, Kbuf, Vt, maskp, ctxb);

  proj_out<<<dim3(128,4),256,0,stream>>>(ctxb, wo, out_b, out);
}

// Round 18
// 169.580 us; speedup vs baseline: 1.3565x; 1.0005x over previous
//
#include <hip/hip_runtime.h>
#include <stdint.h>

typedef _Float16 f16;
typedef __attribute__((ext_vector_type(8))) f16 f16x8;
typedef __attribute__((ext_vector_type(2))) f16 h2;
typedef __attribute__((ext_vector_type(4))) float f32x4;
typedef unsigned short u16;
typedef unsigned int u32;
typedef unsigned char u8;

#define LL 1024
#define DM 512

__device__ __forceinline__ u16 f2h(float f){ return __builtin_bit_cast(u16, (f16)f); }
__device__ __forceinline__ u32 pack2(float a, float b){
  h2 v; v.x = (f16)a; v.y = (f16)b; return __builtin_bit_cast(u32, v);
}
__device__ __forceinline__ f32x4 mfma16h(f16x8 a, f16x8 b, f32x4 c){
  return __builtin_amdgcn_mfma_f32_16x16x32_f16(a, b, c, 0, 0, 0);
}

// ---- DPP 16-lane reductions (row_ror:8/4/2/1), pure VALU, no DS ----
template<int CTRL>
__device__ __forceinline__ float dpp_mov(float x){
  return __builtin_bit_cast(float,
    __builtin_amdgcn_update_dpp(0, __builtin_bit_cast(int, x), CTRL, 0xF, 0xF, true));
}
__device__ __forceinline__ float red_add16(float v){
  v += dpp_mov<0x128>(v);
  v += dpp_mov<0x124>(v);
  v += dpp_mov<0x122>(v);
  v += dpp_mov<0x121>(v);
  return v;
}
__device__ __forceinline__ float red_max16(float v){
  v = fmaxf(v, dpp_mov<0x128>(v));
  v = fmaxf(v, dpp_mov<0x124>(v));
  v = fmaxf(v, dpp_mov<0x122>(v));
  v = fmaxf(v, dpp_mov<0x121>(v));
  return v;
}

// ---------------- fp32 -> f16 convert ----------------
struct CvtArgs {
  const float* src[7];
  u16* dst[7];
  int n4[7];
};

__global__ __launch_bounds__(256) void cvt_kernel(CvtArgs a){
  int seg = blockIdx.y;
  const float4* s = (const float4*)a.src[seg];
  ushort4* d = (ushort4*)a.dst[seg];
  int n4 = a.n4[seg];
  for (int i = blockIdx.x*blockDim.x + threadIdx.x; i < n4; i += gridDim.x*blockDim.x){
    float4 v = s[i];
    ushort4 o;
    o.x = f2h(v.x); o.y = f2h(v.y); o.z = f2h(v.z); o.w = f2h(v.w);
    d[i] = o;
  }
}

// ---------------- fused QKV projection GEMM, 128x128 tile, BK=64 ----------------
// grid (64, 12): which = y>>2 (0=Q,1=K,2=V), nt = y&3.  f16 inputs.
// Staging via global_load_lds width=16; swizzle on GLOBAL source + LDS reads,
// LDS dest linear (rule #21).
struct QkvArgs {
  const u16* A[3];
  const u16* W[3];
  const float* bias[3];
  u16* dst[3];
  float scale[3];
};

__global__ __launch_bounds__(256,2) void proj_qkv(QkvArgs args){
  __shared__ u16 SM[128*128];          // 32 KiB: As(16K)+Bs(16K), reused as stage
  u16* As = SM;
  u16* Bs = SM + 128*64;
  const int tid = threadIdx.x;
  const int w = tid>>6, lane = tid&63;
  const int g = lane>>4, r16 = lane&15;
  const int wr = w>>1, wc = w&1;

  const int which = blockIdx.y>>2, nt = blockIdx.y&3;
  const bool isV = (which==2);
  const u16* A = args.A[which];
  const u16* W = args.W[which];
  const float* bias = args.bias[which];
  u16* dsth = args.dst[which];
  const float scale = args.scale[which];

  const int m0 = blockIdx.x*128, n0 = nt*128;

  f32x4 acc[4][4] = {};

  int rowc[4], slc[4];
  #pragma unroll
  for (int i=0;i<4;++i){
    int c = i*256+tid;
    rowc[i] = c>>3;
    slc[i] = (c&7) ^ ((c>>3)&7);
  }

  const int fswz = r16 & 7;

  for (int k0=0; k0<DM; k0+=64){
    #pragma unroll
    for (int i=0;i<4;++i){
      int c = i*256+tid;
      __builtin_amdgcn_global_load_lds(
        (const __attribute__((address_space(1))) void*)(A + (size_t)(m0+rowc[i])*DM + k0 + slc[i]*8),
        (__attribute__((address_space(3))) void*)(&As[c*8]), 16, 0, 0);
      __builtin_amdgcn_global_load_lds(
        (const __attribute__((address_space(1))) void*)(W + (size_t)(n0+rowc[i])*DM + k0 + slc[i]*8),
        (__attribute__((address_space(3))) void*)(&Bs[c*8]), 16, 0, 0);
    }
    __syncthreads();   // drains vmcnt -> staged LDS ready

    f16x8 af[4][2], bfr[4][2];
    #pragma unroll
    for (int mi=0; mi<4; ++mi){
      int row = wr*64 + mi*16 + r16;
      #pragma unroll
      for (int ks=0; ks<2; ++ks)
        af[mi][ks] = *(const f16x8*)(&As[row*64 + ((ks*4+g)^fswz)*8]);
    }
    #pragma unroll
    for (int ni=0; ni<4; ++ni){
      int row = wc*64 + ni*16 + r16;
      #pragma unroll
      for (int ks=0; ks<2; ++ks)
        bfr[ni][ks] = *(const f16x8*)(&Bs[row*64 + ((ks*4+g)^fswz)*8]);
    }
    if (isV){
      #pragma unroll
      for (int mi=0; mi<4; ++mi)
        #pragma unroll
        for (int ni=0; ni<4; ++ni){
          acc[mi][ni] = mfma16h(af[mi][0], bfr[ni][0], acc[mi][ni]);
          acc[mi][ni] = mfma16h(af[mi][1], bfr[ni][1], acc[mi][ni]);
        }
    } else {
      #pragma unroll
      for (int mi=0; mi<4; ++mi)
        #pragma unroll
        for (int ni=0; ni<4; ++ni){
          acc[mi][ni] = mfma16h(bfr[ni][0], af[mi][0], acc[mi][ni]);
          acc[mi][ni] = mfma16h(bfr[ni][1], af[mi][1], acc[mi][ni]);
        }
    }
    __syncthreads();   // all reads done before next stage overwrites
  }

  // ---- epilogue: stage into chunk-swizzled LDS, then coalesced stores
  if (!isV){
    #pragma unroll
    for (int mi=0; mi<4; ++mi){
      #pragma unroll
      for (int ni=0; ni<4; ++ni){
        f32x4 a = acc[mi][ni];
        int row = wr*64 + mi*16 + r16;
        int c   = wc*16 + ni*4 + g;
        float4 bv = *(const float4*)(bias + n0 + c*4);
        uint2 pk;
        pk.x = pack2((a[0]+bv.x)*scale, (a[1]+bv.y)*scale);
        pk.y = pack2((a[2]+bv.z)*scale, (a[3]+bv.w)*scale);
        *(uint2*)(&SM[row*128 + ((c ^ ((row&7)<<2))<<2)]) = pk;
      }
    }
  } else {
    #pragma unroll
    for (int mi=0; mi<4; ++mi){
      #pragma unroll
      for (int ni=0; ni<4; ++ni){
        f32x4 a = acc[mi][ni];
        int fl = wc*64 + ni*16 + r16;
        int kc = wr*16 + mi*4 + g;
        float bv = bias[n0 + fl];
        uint2 pk;
        pk.x = pack2(a[0]+bv, a[1]+bv);
        pk.y = pack2(a[2]+bv, a[3]+bv);
        *(uint2*)(&SM[fl*128 + ((kc ^ ((fl&7)<<2))<<2)]) = pk;
      }
    }
  }
  __syncthreads();

  #pragma unroll
  for (int rr=0; rr<8; ++rr){
    int row = w*32 + rr*4 + (lane>>4);
    int c0 = (lane&15)*2;
    int cs = c0 ^ ((row&7)<<2);
    uint4 v = *(const uint4*)(&SM[row*128 + (cs<<2)]);
    if (!isV){
      *(uint4*)(dsth + (size_t)(m0+row)*DM + n0 + (c0<<2)) = v;
    } else {
      int n = n0 + row;
      int hh = n>>6, d = n&63, bb = m0>>10;
      *(uint4*)(dsth + (size_t)((bb*8+hh)*64 + d)*1024 + (m0&1023) + (c0<<2)) = v;
    }
  }
}

// ---------------- out-projection GEMM, 64x128 tile, BK=64, grid (128,4) ----------------
__global__ __launch_bounds__(256,2) void proj_out(
    const u16* __restrict__ A, const u16* __restrict__ W,
    const float* __restrict__ bias, float* __restrict__ dstf)
{
  __shared__ u16 As[64*64];
  __shared__ u16 Bs[128*64];
  const int tid = threadIdx.x;
  const int w = tid>>6, lane = tid&63;
  const int g = lane>>4, r16 = lane&15;
  const int m0 = blockIdx.x*64, n0 = blockIdx.y*128;

  f32x4 acc[4][2] = {};

  int rowa[2], slota[2];
  #pragma unroll
  for (int i=0;i<2;++i){ int c = i*256+tid; rowa[i]=c>>3; slota[i]=c&7; }
  int rowb[4], slotb[4];
  #pragma unroll
  for (int i=0;i<4;++i){ int c = i*256+tid; rowb[i]=c>>3; slotb[i]=c&7; }

  uint4 ra[2], rb[4];
  #pragma unroll
  for (int i=0;i<2;++i)
    ra[i] = *(const uint4*)(A + (size_t)(m0+rowa[i])*DM + slota[i]*8);
  #pragma unroll
  for (int i=0;i<4;++i)
    rb[i] = *(const uint4*)(W + (size_t)(n0+rowb[i])*DM + slotb[i]*8);

  const int fswz = r16 & 7;

  for (int k0=0; k0<DM; k0+=64){
    __syncthreads();
    #pragma unroll
    for (int i=0;i<2;++i)
      *(uint4*)(&As[rowa[i]*64 + (slota[i]^(rowa[i]&7))*8]) = ra[i];
    #pragma unroll
    for (int i=0;i<4;++i)
      *(uint4*)(&Bs[rowb[i]*64 + (slotb[i]^(rowb[i]&7))*8]) = rb[i];
    __syncthreads();
    int kn = (k0+64 < DM) ? (k0+64) : 0;
    #pragma unroll
    for (int i=0;i<2;++i)
      ra[i] = *(const uint4*)(A + (size_t)(m0+rowa[i])*DM + kn + slota[i]*8);
    #pragma unroll
    for (int i=0;i<4;++i)
      rb[i] = *(const uint4*)(W + (size_t)(n0+rowb[i])*DM + kn + slotb[i]*8);

    f16x8 af[4][2], bfr[2][2];
    #pragma unroll
    for (int mi=0; mi<4; ++mi){
      int row = mi*16 + r16;
      #pragma unroll
      for (int ks=0; ks<2; ++ks)
        af[mi][ks] = *(const f16x8*)(&As[row*64 + ((ks*4+g)^fswz)*8]);
    }
    #pragma unroll
    for (int ni=0; ni<2; ++ni){
      int row = w*32 + ni*16 + r16;
      #pragma unroll
      for (int ks=0; ks<2; ++ks)
        bfr[ni][ks] = *(const f16x8*)(&Bs[row*64 + ((ks*4+g)^fswz)*8]);
    }
    #pragma unroll
    for (int mi=0; mi<4; ++mi)
      #pragma unroll
      for (int ni=0; ni<2; ++ni){
        acc[mi][ni] = mfma16h(bfr[ni][0], af[mi][0], acc[mi][ni]);
        acc[mi][ni] = mfma16h(bfr[ni][1], af[mi][1], acc[mi][ni]);
      }
  }

  #pragma unroll
  for (int mi=0; mi<4; ++mi){
    #pragma unroll
    for (int ni=0; ni<2; ++ni){
      int m  = m0 + mi*16 + r16;
      int nb = n0 + w*32 + ni*16 + g*4;
      float4 bv = *(const float4*)(bias + nb);
      float4 o;
      o.x = acc[mi][ni][0]+bv.x; o.y = acc[mi][ni][1]+bv.y;
      o.z = acc[mi][ni][2]+bv.z; o.w = acc[mi][ni][3]+bv.w;
      *(float4*)(dstf + (size_t)m*DM + nb) = o;
    }
  }
}

// ---------------- fused attention + entmax-1.5 (r17 + pinned C prefetch) -------
// grid 2048, 512 threads (8 waves): bh = ((bid&7)<<3)|((bid>>3)&7), qb = bid>>6.
// 32 q-rows/block, S[32][1024] f16 = 64 KiB (2 blocks/CU).
// Phase A: full 16-load K burst + sched_barrier(0) pin (r17: -10us, validated
// that r11's prefetch null was compiler load-sinking).
// Phase C: same pin applied — prefetch loads forced to issue before the MFMA
// cluster each group. Phase B: LDS burst pinned before max-tree.
// Newton 5 iters + finalize. setprio on C MFMAs.
// Swizzle: (row,k) at u16 off row*1024 + (k^(cc<<3)), cc = ((k>>6)&7) ^ (row&7).
__global__ __launch_bounds__(512,4) void attn_entmax(
    const u16* __restrict__ Qf, const u16* __restrict__ Kf,
    const u16* __restrict__ Vt, const u8* __restrict__ mask,
    u16* __restrict__ ctx)
{
  __shared__ u16 S[32*1024];   // 64 KiB

  const int tid = threadIdx.x, w = tid>>6, lane = tid&63;
  const int g = lane>>4, r16 = lane&15;
  const int bid = blockIdx.x;
  const int bh = ((bid&7)<<3) | ((bid>>3)&7);
  const int qb = bid>>6;
  const int b = bh>>3, h = bh&7;
  const int q0 = qb*32;
  const u16* Qb = Qf + ((size_t)(b*LL + q0))*DM + h*64;
  const u16* Kb = Kf + ((size_t)(b*LL))*DM + h*64;

  // ---- Phase A: S^T = K Q^T (scale folded into Q); wave w: keys [w*128,+128)
  f16x8 qf[2][2];
  #pragma unroll
  for (int qi=0;qi<2;++qi){
    qf[qi][0] = *(const f16x8*)(Qb + (size_t)(qi*16 + r16)*DM + g*8);
    qf[qi][1] = *(const f16x8*)(Qb + (size_t)(qi*16 + r16)*DM + 32 + g*8);
  }
  {
    f16x8 kr0[8], kr1[8];
    u32 m4a[8];
    #pragma unroll
    for (int kt=0;kt<8;++kt){
      const u16* kp = Kb + (size_t)(w*128 + kt*16 + r16)*DM + g*8;
      kr0[kt] = *(const f16x8*)(kp);
      kr1[kt] = *(const f16x8*)(kp + 32);
      m4a[kt] = *(const u32*)(mask + b*LL + w*128 + kt*16 + g*4);
    }
    __builtin_amdgcn_sched_barrier(0);   // pin: all 16 loads issued before use
    #pragma unroll
    for (int kt=0;kt<8;++kt){
      int kb = w*128 + kt*16 + g*4;
      u32 m4 = m4a[kt];
      #pragma unroll
      for (int qi=0; qi<2; ++qi){
        f32x4 acc = {};
        acc = mfma16h(kr0[kt], qf[qi][0], acc);   // reg-dim: key, col: q=r16
        acc = mfma16h(kr1[kt], qf[qi][1], acc);
        float v0 = (m4 & 0xFFu)       ? -30000.f : acc[0];
        float v1 = (m4 & 0xFF00u)     ? -30000.f : acc[1];
        float v2 = (m4 & 0xFF0000u)   ? -30000.f : acc[2];
        float v3 = (m4 & 0xFF000000u) ? -30000.f : acc[3];
        int row = qi*16 + r16;
        int cc = ((kb>>6)&7) ^ (row&7);
        uint2 pk; pk.x = pack2(v0,v1); pk.y = pack2(v2,v3);
        *(uint2*)(&S[row*LL + (kb ^ (cc<<3))]) = pk;
      }
    }
  }
  __syncthreads();

  // ---- Phase B: entmax-1.5; row = w*4+g (4 rows/wave in parallel),
  // lane r16 holds 64 contiguous keys as 32 h2; all-DPP reduces; 5 Newton iters.
  {
    const int r = w*4 + g;
    const int ccb = (r16 ^ r) & 7;
    h2 zp[32];
    #pragma unroll
    for (int c=0;c<8;++c){
      uint4 v = *(const uint4*)(&S[r*LL + ((r16*64 + c*8) ^ (ccb<<3))]);
      zp[c*4+0] = __builtin_bit_cast(h2, v.x);
      zp[c*4+1] = __builtin_bit_cast(h2, v.y);
      zp[c*4+2] = __builtin_bit_cast(h2, v.z);
      zp[c*4+3] = __builtin_bit_cast(h2, v.w);
    }
    __builtin_amdgcn_sched_barrier(0);   // pin: all 8 ds_read_b128 in flight
    h2 m2 = zp[0];
    #pragma unroll
    for (int t=1;t<32;++t) m2 = __builtin_elementwise_max(m2, zp[t]);
    float mx = red_max16(fmaxf((float)m2.x, (float)m2.y));

    const h2 zero2 = (h2)(f16)0;
    float lo = mx - 1.0f, hi = mx, tau = mx - 0.5f;
    #pragma unroll 1
    for (int it=0; it<5; ++it){
      f16 th = (f16)tau;
      h2 t2; t2.x = th; t2.y = th;
      h2 s1a = zero2, s1b = zero2, s2a = zero2, s2b = zero2;
      #pragma unroll
      for (int t=0;t<32;t+=2){
        h2 d0 = __builtin_elementwise_max(zp[t]   - t2, zero2);
        h2 d1 = __builtin_elementwise_max(zp[t+1] - t2, zero2);
        s1a = s1a + d0;        s1b = s1b + d1;
        s2a = s2a + d0*d0;     s2b = s2b + d1*d1;
      }
      h2 s1h = s1a + s1b, s2h = s2a + s2b;
      float s1 = red_add16((float)s1h.x + (float)s1h.y);
      float s2 = red_add16((float)s2h.x + (float)s2h.y);
      if (s2 >= 1.0f) lo = tau; else hi = tau;
      float tn = tau + (s2 - 1.0f)/(2.0f*s1);
      tau = (tn >= lo && tn < hi) ? tn : 0.5f*(lo+hi);
    }

    {
      f16 th = (f16)tau;
      h2 t2; t2.x = th; t2.y = th;
      h2 psa = zero2, psb = zero2;
      #pragma unroll
      for (int t=0;t<32;t+=2){
        h2 d0 = __builtin_elementwise_max(zp[t]   - t2, zero2);
        h2 d1 = __builtin_elementwise_max(zp[t+1] - t2, zero2);
        h2 p0 = d0*d0, p1 = d1*d1;
        zp[t] = p0; zp[t+1] = p1;
        psa = psa + p0; psb = psb + p1;
      }
      h2 ps2 = psa + psb;
      float ps = red_add16((float)ps2.x + (float)ps2.y);
      f16 iv = (f16)(1.0f/ps);
      h2 i2; i2.x = iv; i2.y = iv;
      #pragma unroll
      for (int c=0;c<8;++c){
        uint4 v;
        v.x = __builtin_bit_cast(u32, (h2)(zp[c*4+0]*i2));
        v.y = __builtin_bit_cast(u32, (h2)(zp[c*4+1]*i2));
        v.z = __builtin_bit_cast(u32, (h2)(zp[c*4+2]*i2));
        v.w = __builtin_bit_cast(u32, (h2)(zp[c*4+3]*i2));
        *(uint4*)(&S[r*LL + ((r16*64 + c*8) ^ (ccb<<3))]) = v;  // same slots read
      }
    }
  }
  __syncthreads();

  // ---- Phase C: ctx = P @ V ; wave w -> q-tile (w>>2), d-tile (w&3);
  // P(LDS) + V(L2) loads double-buffered 4 kt ahead, prefetch PINNED before
  // the MFMA cluster each group (same mechanism as phase A's fix).
  const int qi = w>>2, di = w&3;
  const u16* vrow = Vt + (size_t)(bh*64 + di*16 + r16)*LL;
  const int prow = qi*16 + r16;
  f32x4 o0 = {}, o1 = {};
  {
    f16x8 pc[4], vc[4], pn[4], vn[4];
    #pragma unroll
    for (int j=0;j<4;++j){
      int k = j*32 + g*8;
      int cc = ((k>>6)&7) ^ (prow&7);
      pc[j] = *(const f16x8*)(&S[prow*LL + (k ^ (cc<<3))]);
      vc[j] = *(const f16x8*)(vrow + k);
    }
    #pragma unroll
    for (int grp=0; grp<8; ++grp){
      #pragma unroll
      for (int j=0;j<4;++j){
        if (grp < 7){
          int k = (grp*4+4+j)*32 + g*8;
          int cc = ((k>>6)&7) ^ (prow&7);
          pn[j] = *(const f16x8*)(&S[prow*LL + (k ^ (cc<<3))]);
          vn[j] = *(const f16x8*)(vrow + k);
        }
      }
      __builtin_amdgcn_sched_barrier(0);  // pin: prefetch issued before MFMAs
      __builtin_amdgcn_s_setprio(1);
      #pragma unroll
      for (int j=0;j<4;++j){
        if (j & 1) o1 = mfma16h(pc[j], vc[j], o1);
        else       o0 = mfma16h(pc[j], vc[j], o0);
      }
      __builtin_amdgcn_s_setprio(0);
      #pragma unroll
      for (int j=0;j<4;++j){ pc[j]=pn[j]; vc[j]=vn[j]; }
    }
  }
  #pragma unroll
  for (int r=0;r<4;++r){
    int q = q0 + qi*16 + g*4 + r;
    ctx[(size_t)(b*LL + q)*DM + h*64 + di*16 + r16] = f2h(o0[r] + o1[r]);
  }
}

// ---------------- launch ----------------
extern "C" void kernel_launch(void* const* d_in, const int* in_sizes, int n_in,
                              void* d_out, int out_size, void* d_ws, size_t ws_size,
                              hipStream_t stream) {
  const float* query = (const float*)d_in[0];
  const float* key   = (const float*)d_in[1];
  const float* value = (const float*)d_in[2];
  const u8*    maskp = (const u8*)d_in[3];
  const float* q_w = (const float*)d_in[4];
  const float* q_b = (const float*)d_in[5];
  const float* k_w = (const float*)d_in[6];
  const float* k_b = (const float*)d_in[7];
  const float* v_w = (const float*)d_in[8];
  const float* v_b = (const float*)d_in[9];
  const float* out_w = (const float*)d_in[10];
  const float* out_b = (const float*)d_in[11];
  float* out = (float*)d_out;

  u16* qx = (u16*)d_ws;                 // 4M f16 elems each
  u16* kx = qx + 4194304;
  u16* vx = kx + 4194304;
  u16* wq = vx + 4194304;               // 256K elems each
  u16* wk = wq + 262144;
  u16* wv = wk + 262144;
  u16* wo = wv + 262144;
  u16* Qbuf = wo + 262144;              // 4M elems each
  u16* Kbuf = Qbuf + 4194304;
  u16* Vt   = Kbuf + 4194304;
  u16* ctxb = Vt + 4194304;

  CvtArgs ca;
  ca.src[0]=query; ca.dst[0]=qx; ca.n4[0]=8*LL*DM/4;
  ca.src[1]=key;   ca.dst[1]=kx; ca.n4[1]=8*LL*DM/4;
  ca.src[2]=value; ca.dst[2]=vx; ca.n4[2]=8*LL*DM/4;
  ca.src[3]=q_w;   ca.dst[3]=wq; ca.n4[3]=DM*DM/4;
  ca.src[4]=k_w;   ca.dst[4]=wk; ca.n4[4]=DM*DM/4;
  ca.src[5]=v_w;   ca.dst[5]=wv; ca.n4[5]=DM*DM/4;
  ca.src[6]=out_w; ca.dst[6]=wo; ca.n4[6]=DM*DM/4;
  cvt_kernel<<<dim3(512,7),256,0,stream>>>(ca);

  QkvArgs qa;
  qa.A[0]=qx; qa.A[1]=kx; qa.A[2]=vx;
  qa.W[0]=wq; qa.W[1]=wk; qa.W[2]=wv;
  qa.bias[0]=q_b; qa.bias[1]=k_b; qa.bias[2]=v_b;
  qa.dst[0]=Qbuf; qa.dst[1]=Kbuf; qa.dst[2]=Vt;
  qa.scale[0]=0.0625f; qa.scale[1]=1.0f; qa.scale[2]=1.0f; // 1/8 (dh^-0.5) * 1/2 on Q

  proj_qkv<<<dim3(64,12),256,0,stream>>>(qa);

  attn_entmax<<<dim3(2048),512,0,stream>>>(Qbuf, Kbuf, Vt, maskp, ctxb);

  proj_out<<<dim3(128,4),256,0,stream>>>(ctxb, wo, out_b, out);
}

// Round 19
// 167.315 us; speedup vs baseline: 1.3749x; 1.0135x over previous
//
#include <hip/hip_runtime.h>
#include <stdint.h>

typedef _Float16 f16;
typedef __attribute__((ext_vector_type(8))) f16 f16x8;
typedef __attribute__((ext_vector_type(2))) f16 h2;
typedef __attribute__((ext_vector_type(4))) float f32x4;
typedef unsigned short u16;
typedef unsigned int u32;
typedef unsigned char u8;

#define LL 1024
#define DM 512

__device__ __forceinline__ u16 f2h(float f){ return __builtin_bit_cast(u16, (f16)f); }
__device__ __forceinline__ u32 pack2(float a, float b){
  h2 v; v.x = (f16)a; v.y = (f16)b; return __builtin_bit_cast(u32, v);
}
__device__ __forceinline__ f32x4 mfma16h(f16x8 a, f16x8 b, f32x4 c){
  return __builtin_amdgcn_mfma_f32_16x16x32_f16(a, b, c, 0, 0, 0);
}
// load 8 consecutive f32, convert to 8 packed f16 (RNE, same as cvt kernel)
__device__ __forceinline__ uint4 ldcvt8(const float* p){
  float4 a = *(const float4*)p;
  float4 b = *(const float4*)(p+4);
  uint4 r;
  r.x = pack2(a.x,a.y); r.y = pack2(a.z,a.w);
  r.z = pack2(b.x,b.y); r.w = pack2(b.z,b.w);
  return r;
}

// ---- DPP 16-lane reductions (row_ror:8/4/2/1), pure VALU, no DS ----
template<int CTRL>
__device__ __forceinline__ float dpp_mov(float x){
  return __builtin_bit_cast(float,
    __builtin_amdgcn_update_dpp(0, __builtin_bit_cast(int, x), CTRL, 0xF, 0xF, true));
}
__device__ __forceinline__ float red_add16(float v){
  v += dpp_mov<0x128>(v);
  v += dpp_mov<0x124>(v);
  v += dpp_mov<0x122>(v);
  v += dpp_mov<0x121>(v);
  return v;
}
__device__ __forceinline__ float red_max16(float v){
  v = fmaxf(v, dpp_mov<0x128>(v));
  v = fmaxf(v, dpp_mov<0x124>(v));
  v = fmaxf(v, dpp_mov<0x122>(v));
  v = fmaxf(v, dpp_mov<0x121>(v));
  return v;
}

// ---------------- fp32 -> f16 convert (WEIGHTS ONLY now, 2 MB total) ----------
struct CvtArgs {
  const float* src[4];
  u16* dst[4];
  int n4[4];
};

__global__ __launch_bounds__(256) void cvt_kernel(CvtArgs a){
  int seg = blockIdx.y;
  const float4* s = (const float4*)a.src[seg];
  ushort4* d = (ushort4*)a.dst[seg];
  int n4 = a.n4[seg];
  for (int i = blockIdx.x*blockDim.x + threadIdx.x; i < n4; i += gridDim.x*blockDim.x){
    float4 v = s[i];
    ushort4 o;
    o.x = f2h(v.x); o.y = f2h(v.y); o.z = f2h(v.z); o.w = f2h(v.w);
    d[i] = o;
  }
}

// ---------------- fused QKV projection GEMM, 128x128 tile, BK=64 ----------------
// grid (64, 12): which = y>>2 (0=Q,1=K,2=V), nt = y&3.
// A = fp32 input, converted during register staging (kills the big cvt pass;
// r5's failure was the scatter epilogue, not input staging — epilogue here
// stays LDS-staged/coalesced). W = f16 via global_load_lds (rule #21 swizzle).
struct QkvArgs {
  const float* A[3];
  const u16* W[3];
  const float* bias[3];
  u16* dst[3];
  float scale[3];
};

__global__ __launch_bounds__(256,2) void proj_qkv(QkvArgs args){
  __shared__ u16 SM[128*128];          // 32 KiB: As(16K)+Bs(16K), reused as stage
  u16* As = SM;
  u16* Bs = SM + 128*64;
  const int tid = threadIdx.x;
  const int w = tid>>6, lane = tid&63;
  const int g = lane>>4, r16 = lane&15;
  const int wr = w>>1, wc = w&1;

  const int which = blockIdx.y>>2, nt = blockIdx.y&3;
  const bool isV = (which==2);
  const float* A = args.A[which];
  const u16* W = args.W[which];
  const float* bias = args.bias[which];
  u16* dsth = args.dst[which];
  const float scale = args.scale[which];

  const int m0 = blockIdx.x*128, n0 = nt*128;

  f32x4 acc[4][4] = {};

  int rowc[4], slc[4];
  #pragma unroll
  for (int i=0;i<4;++i){
    int c = i*256+tid;
    rowc[i] = c>>3;
    slc[i] = (c&7) ^ ((c>>3)&7);
  }

  const int fswz = r16 & 7;

  for (int k0=0; k0<DM; k0+=64){
    // A: fp32 load + cvt in regs (issued first, 8 dwordx4 in flight)
    uint4 av[4];
    #pragma unroll
    for (int i=0;i<4;++i)
      av[i] = ldcvt8(A + (size_t)(m0+rowc[i])*DM + k0 + slc[i]*8);
    // W: f16 direct-to-LDS
    #pragma unroll
    for (int i=0;i<4;++i){
      int c = i*256+tid;
      __builtin_amdgcn_global_load_lds(
        (const __attribute__((address_space(1))) void*)(W + (size_t)(n0+rowc[i])*DM + k0 + slc[i]*8),
        (__attribute__((address_space(3))) void*)(&Bs[c*8]), 16, 0, 0);
    }
    #pragma unroll
    for (int i=0;i<4;++i)
      *(uint4*)(&As[(i*256+tid)*8]) = av[i];
    __syncthreads();   // drains vmcnt + lgkm -> staged LDS ready

    f16x8 af[4][2], bfr[4][2];
    #pragma unroll
    for (int mi=0; mi<4; ++mi){
      int row = wr*64 + mi*16 + r16;
      #pragma unroll
      for (int ks=0; ks<2; ++ks)
        af[mi][ks] = *(const f16x8*)(&As[row*64 + ((ks*4+g)^fswz)*8]);
    }
    #pragma unroll
    for (int ni=0; ni<4; ++ni){
      int row = wc*64 + ni*16 + r16;
      #pragma unroll
      for (int ks=0; ks<2; ++ks)
        bfr[ni][ks] = *(const f16x8*)(&Bs[row*64 + ((ks*4+g)^fswz)*8]);
    }
    if (isV){
      #pragma unroll
      for (int mi=0; mi<4; ++mi)
        #pragma unroll
        for (int ni=0; ni<4; ++ni){
          acc[mi][ni] = mfma16h(af[mi][0], bfr[ni][0], acc[mi][ni]);
          acc[mi][ni] = mfma16h(af[mi][1], bfr[ni][1], acc[mi][ni]);
        }
    } else {
      #pragma unroll
      for (int mi=0; mi<4; ++mi)
        #pragma unroll
        for (int ni=0; ni<4; ++ni){
          acc[mi][ni] = mfma16h(bfr[ni][0], af[mi][0], acc[mi][ni]);
          acc[mi][ni] = mfma16h(bfr[ni][1], af[mi][1], acc[mi][ni]);
        }
    }
    __syncthreads();   // all reads done before next stage overwrites
  }

  // ---- epilogue: stage into chunk-swizzled LDS, then coalesced stores
  if (!isV){
    #pragma unroll
    for (int mi=0; mi<4; ++mi){
      #pragma unroll
      for (int ni=0; ni<4; ++ni){
        f32x4 a = acc[mi][ni];
        int row = wr*64 + mi*16 + r16;
        int c   = wc*16 + ni*4 + g;
        float4 bv = *(const float4*)(bias + n0 + c*4);
        uint2 pk;
        pk.x = pack2((a[0]+bv.x)*scale, (a[1]+bv.y)*scale);
        pk.y = pack2((a[2]+bv.z)*scale, (a[3]+bv.w)*scale);
        *(uint2*)(&SM[row*128 + ((c ^ ((row&7)<<2))<<2)]) = pk;
      }
    }
  } else {
    #pragma unroll
    for (int mi=0; mi<4; ++mi){
      #pragma unroll
      for (int ni=0; ni<4; ++ni){
        f32x4 a = acc[mi][ni];
        int fl = wc*64 + ni*16 + r16;
        int kc = wr*16 + mi*4 + g;
        float bv = bias[n0 + fl];
        uint2 pk;
        pk.x = pack2(a[0]+bv, a[1]+bv);
        pk.y = pack2(a[2]+bv, a[3]+bv);
        *(uint2*)(&SM[fl*128 + ((kc ^ ((fl&7)<<2))<<2)]) = pk;
      }
    }
  }
  __syncthreads();

  #pragma unroll
  for (int rr=0; rr<8; ++rr){
    int row = w*32 + rr*4 + (lane>>4);
    int c0 = (lane&15)*2;
    int cs = c0 ^ ((row&7)<<2);
    uint4 v = *(const uint4*)(&SM[row*128 + (cs<<2)]);
    if (!isV){
      *(uint4*)(dsth + (size_t)(m0+row)*DM + n0 + (c0<<2)) = v;
    } else {
      int n = n0 + row;
      int hh = n>>6, d = n&63, bb = m0>>10;
      *(uint4*)(dsth + (size_t)((bb*8+hh)*64 + d)*1024 + (m0&1023) + (c0<<2)) = v;
    }
  }
}

// ---------------- out-projection GEMM, 64x128 tile, BK=64, grid (128,4) ----------------
__global__ __launch_bounds__(256,2) void proj_out(
    const u16* __restrict__ A, const u16* __restrict__ W,
    const float* __restrict__ bias, float* __restrict__ dstf)
{
  __shared__ u16 As[64*64];
  __shared__ u16 Bs[128*64];
  const int tid = threadIdx.x;
  const int w = tid>>6, lane = tid&63;
  const int g = lane>>4, r16 = lane&15;
  const int m0 = blockIdx.x*64, n0 = blockIdx.y*128;

  f32x4 acc[4][2] = {};

  int rowa[2], slota[2];
  #pragma unroll
  for (int i=0;i<2;++i){ int c = i*256+tid; rowa[i]=c>>3; slota[i]=c&7; }
  int rowb[4], slotb[4];
  #pragma unroll
  for (int i=0;i<4;++i){ int c = i*256+tid; rowb[i]=c>>3; slotb[i]=c&7; }

  uint4 ra[2], rb[4];
  #pragma unroll
  for (int i=0;i<2;++i)
    ra[i] = *(const uint4*)(A + (size_t)(m0+rowa[i])*DM + slota[i]*8);
  #pragma unroll
  for (int i=0;i<4;++i)
    rb[i] = *(const uint4*)(W + (size_t)(n0+rowb[i])*DM + slotb[i]*8);

  const int fswz = r16 & 7;

  for (int k0=0; k0<DM; k0+=64){
    __syncthreads();
    #pragma unroll
    for (int i=0;i<2;++i)
      *(uint4*)(&As[rowa[i]*64 + (slota[i]^(rowa[i]&7))*8]) = ra[i];
    #pragma unroll
    for (int i=0;i<4;++i)
      *(uint4*)(&Bs[rowb[i]*64 + (slotb[i]^(rowb[i]&7))*8]) = rb[i];
    __syncthreads();
    int kn = (k0+64 < DM) ? (k0+64) : 0;
    #pragma unroll
    for (int i=0;i<2;++i)
      ra[i] = *(const uint4*)(A + (size_t)(m0+rowa[i])*DM + kn + slota[i]*8);
    #pragma unroll
    for (int i=0;i<4;++i)
      rb[i] = *(const uint4*)(W + (size_t)(n0+rowb[i])*DM + kn + slotb[i]*8);

    f16x8 af[4][2], bfr[2][2];
    #pragma unroll
    for (int mi=0; mi<4; ++mi){
      int row = mi*16 + r16;
      #pragma unroll
      for (int ks=0; ks<2; ++ks)
        af[mi][ks] = *(const f16x8*)(&As[row*64 + ((ks*4+g)^fswz)*8]);
    }
    #pragma unroll
    for (int ni=0; ni<2; ++ni){
      int row = w*32 + ni*16 + r16;
      #pragma unroll
      for (int ks=0; ks<2; ++ks)
        bfr[ni][ks] = *(const f16x8*)(&Bs[row*64 + ((ks*4+g)^fswz)*8]);
    }
    #pragma unroll
    for (int mi=0; mi<4; ++mi)
      #pragma unroll
      for (int ni=0; ni<2; ++ni){
        acc[mi][ni] = mfma16h(bfr[ni][0], af[mi][0], acc[mi][ni]);
        acc[mi][ni] = mfma16h(bfr[ni][1], af[mi][1], acc[mi][ni]);
      }
  }

  #pragma unroll
  for (int mi=0; mi<4; ++mi){
    #pragma unroll
    for (int ni=0; ni<2; ++ni){
      int m  = m0 + mi*16 + r16;
      int nb = n0 + w*32 + ni*16 + g*4;
      float4 bv = *(const float4*)(bias + nb);
      float4 o;
      o.x = acc[mi][ni][0]+bv.x; o.y = acc[mi][ni][1]+bv.y;
      o.z = acc[mi][ni][2]+bv.z; o.w = acc[mi][ni][3]+bv.w;
      *(float4*)(dstf + (size_t)m*DM + nb) = o;
    }
  }
}

// ---------------- fused attention + entmax-1.5 (r18, measured floor) -----------
// grid 2048, 512 threads (8 waves): bh = ((bid&7)<<3)|((bid>>3)&7), qb = bid>>6.
// 32 q-rows/block, S[32][1024] f16 = 64 KiB (2 blocks/CU).
// Phase A: 16-load K burst + sched_barrier(0) pin (r17: -10us). B/C pins null
// (r18) but harmless. Newton 5 iters + finalize. setprio on C MFMAs.
// Swizzle: (row,k) at u16 off row*1024 + (k^(cc<<3)), cc = ((k>>6)&7) ^ (row&7).
__global__ __launch_bounds__(512,4) void attn_entmax(
    const u16* __restrict__ Qf, const u16* __restrict__ Kf,
    const u16* __restrict__ Vt, const u8* __restrict__ mask,
    u16* __restrict__ ctx)
{
  __shared__ u16 S[32*1024];   // 64 KiB

  const int tid = threadIdx.x, w = tid>>6, lane = tid&63;
  const int g = lane>>4, r16 = lane&15;
  const int bid = blockIdx.x;
  const int bh = ((bid&7)<<3) | ((bid>>3)&7);
  const int qb = bid>>6;
  const int b = bh>>3, h = bh&7;
  const int q0 = qb*32;
  const u16* Qb = Qf + ((size_t)(b*LL + q0))*DM + h*64;
  const u16* Kb = Kf + ((size_t)(b*LL))*DM + h*64;

  // ---- Phase A: S^T = K Q^T (scale folded into Q); wave w: keys [w*128,+128)
  f16x8 qf[2][2];
  #pragma unroll
  for (int qi=0;qi<2;++qi){
    qf[qi][0] = *(const f16x8*)(Qb + (size_t)(qi*16 + r16)*DM + g*8);
    qf[qi][1] = *(const f16x8*)(Qb + (size_t)(qi*16 + r16)*DM + 32 + g*8);
  }
  {
    f16x8 kr0[8], kr1[8];
    u32 m4a[8];
    #pragma unroll
    for (int kt=0;kt<8;++kt){
      const u16* kp = Kb + (size_t)(w*128 + kt*16 + r16)*DM + g*8;
      kr0[kt] = *(const f16x8*)(kp);
      kr1[kt] = *(const f16x8*)(kp + 32);
      m4a[kt] = *(const u32*)(mask + b*LL + w*128 + kt*16 + g*4);
    }
    __builtin_amdgcn_sched_barrier(0);   // pin: all 16 loads issued before use
    #pragma unroll
    for (int kt=0;kt<8;++kt){
      int kb = w*128 + kt*16 + g*4;
      u32 m4 = m4a[kt];
      #pragma unroll
      for (int qi=0; qi<2; ++qi){
        f32x4 acc = {};
        acc = mfma16h(kr0[kt], qf[qi][0], acc);   // reg-dim: key, col: q=r16
        acc = mfma16h(kr1[kt], qf[qi][1], acc);
        float v0 = (m4 & 0xFFu)       ? -30000.f : acc[0];
        float v1 = (m4 & 0xFF00u)     ? -30000.f : acc[1];
        float v2 = (m4 & 0xFF0000u)   ? -30000.f : acc[2];
        float v3 = (m4 & 0xFF000000u) ? -30000.f : acc[3];
        int row = qi*16 + r16;
        int cc = ((kb>>6)&7) ^ (row&7);
        uint2 pk; pk.x = pack2(v0,v1); pk.y = pack2(v2,v3);
        *(uint2*)(&S[row*LL + (kb ^ (cc<<3))]) = pk;
      }
    }
  }
  __syncthreads();

  // ---- Phase B: entmax-1.5; row = w*4+g (4 rows/wave in parallel),
  // lane r16 holds 64 contiguous keys as 32 h2; all-DPP reduces; 5 Newton iters.
  {
    const int r = w*4 + g;
    const int ccb = (r16 ^ r) & 7;
    h2 zp[32];
    #pragma unroll
    for (int c=0;c<8;++c){
      uint4 v = *(const uint4*)(&S[r*LL + ((r16*64 + c*8) ^ (ccb<<3))]);
      zp[c*4+0] = __builtin_bit_cast(h2, v.x);
      zp[c*4+1] = __builtin_bit_cast(h2, v.y);
      zp[c*4+2] = __builtin_bit_cast(h2, v.z);
      zp[c*4+3] = __builtin_bit_cast(h2, v.w);
    }
    __builtin_amdgcn_sched_barrier(0);   // pin: all 8 ds_read_b128 in flight
    h2 m2 = zp[0];
    #pragma unroll
    for (int t=1;t<32;++t) m2 = __builtin_elementwise_max(m2, zp[t]);
    float mx = red_max16(fmaxf((float)m2.x, (float)m2.y));

    const h2 zero2 = (h2)(f16)0;
    float lo = mx - 1.0f, hi = mx, tau = mx - 0.5f;
    #pragma unroll 1
    for (int it=0; it<5; ++it){
      f16 th = (f16)tau;
      h2 t2; t2.x = th; t2.y = th;
      h2 s1a = zero2, s1b = zero2, s2a = zero2, s2b = zero2;
      #pragma unroll
      for (int t=0;t<32;t+=2){
        h2 d0 = __builtin_elementwise_max(zp[t]   - t2, zero2);
        h2 d1 = __builtin_elementwise_max(zp[t+1] - t2, zero2);
        s1a = s1a + d0;        s1b = s1b + d1;
        s2a = s2a + d0*d0;     s2b = s2b + d1*d1;
      }
      h2 s1h = s1a + s1b, s2h = s2a + s2b;
      float s1 = red_add16((float)s1h.x + (float)s1h.y);
      float s2 = red_add16((float)s2h.x + (float)s2h.y);
      if (s2 >= 1.0f) lo = tau; else hi = tau;
      float tn = tau + (s2 - 1.0f)/(2.0f*s1);
      tau = (tn >= lo && tn < hi) ? tn : 0.5f*(lo+hi);
    }

    {
      f16 th = (f16)tau;
      h2 t2; t2.x = th; t2.y = th;
      h2 psa = zero2, psb = zero2;
      #pragma unroll
      for (int t=0;t<32;t+=2){
        h2 d0 = __builtin_elementwise_max(zp[t]   - t2, zero2);
        h2 d1 = __builtin_elementwise_max(zp[t+1] - t2, zero2);
        h2 p0 = d0*d0, p1 = d1*d1;
        zp[t] = p0; zp[t+1] = p1;
        psa = psa + p0; psb = psb + p1;
      }
      h2 ps2 = psa + psb;
      float ps = red_add16((float)ps2.x + (float)ps2.y);
      f16 iv = (f16)(1.0f/ps);
      h2 i2; i2.x = iv; i2.y = iv;
      #pragma unroll
      for (int c=0;c<8;++c){
        uint4 v;
        v.x = __builtin_bit_cast(u32, (h2)(zp[c*4+0]*i2));
        v.y = __builtin_bit_cast(u32, (h2)(zp[c*4+1]*i2));
        v.z = __builtin_bit_cast(u32, (h2)(zp[c*4+2]*i2));
        v.w = __builtin_bit_cast(u32, (h2)(zp[c*4+3]*i2));
        *(uint4*)(&S[r*LL + ((r16*64 + c*8) ^ (ccb<<3))]) = v;  // same slots read
      }
    }
  }
  __syncthreads();

  // ---- Phase C: ctx = P @ V ; wave w -> q-tile (w>>2), d-tile (w&3);
  // P(LDS) + V(L2) loads double-buffered 4 kt ahead, prefetch pinned.
  const int qi = w>>2, di = w&3;
  const u16* vrow = Vt + (size_t)(bh*64 + di*16 + r16)*LL;
  const int prow = qi*16 + r16;
  f32x4 o0 = {}, o1 = {};
  {
    f16x8 pc[4], vc[4], pn[4], vn[4];
    #pragma unroll
    for (int j=0;j<4;++j){
      int k = j*32 + g*8;
      int cc = ((k>>6)&7) ^ (prow&7);
      pc[j] = *(const f16x8*)(&S[prow*LL + (k ^ (cc<<3))]);
      vc[j] = *(const f16x8*)(vrow + k);
    }
    #pragma unroll
    for (int grp=0; grp<8; ++grp){
      #pragma unroll
      for (int j=0;j<4;++j){
        if (grp < 7){
          int k = (grp*4+4+j)*32 + g*8;
          int cc = ((k>>6)&7) ^ (prow&7);
          pn[j] = *(const f16x8*)(&S[prow*LL + (k ^ (cc<<3))]);
          vn[j] = *(const f16x8*)(vrow + k);
        }
      }
      __builtin_amdgcn_sched_barrier(0);  // pin: prefetch issued before MFMAs
      __builtin_amdgcn_s_setprio(1);
      #pragma unroll
      for (int j=0;j<4;++j){
        if (j & 1) o1 = mfma16h(pc[j], vc[j], o1);
        else       o0 = mfma16h(pc[j], vc[j], o0);
      }
      __builtin_amdgcn_s_setprio(0);
      #pragma unroll
      for (int j=0;j<4;++j){ pc[j]=pn[j]; vc[j]=vn[j]; }
    }
  }
  #pragma unroll
  for (int r=0;r<4;++r){
    int q = q0 + qi*16 + g*4 + r;
    ctx[(size_t)(b*LL + q)*DM + h*64 + di*16 + r16] = f2h(o0[r] + o1[r]);
  }
}

// ---------------- launch ----------------
extern "C" void kernel_launch(void* const* d_in, const int* in_sizes, int n_in,
                              void* d_out, int out_size, void* d_ws, size_t ws_size,
                              hipStream_t stream) {
  const float* query = (const float*)d_in[0];
  const float* key   = (const float*)d_in[1];
  const float* value = (const float*)d_in[2];
  const u8*    maskp = (const u8*)d_in[3];
  const float* q_w = (const float*)d_in[4];
  const float* q_b = (const float*)d_in[5];
  const float* k_w = (const float*)d_in[6];
  const float* k_b = (const float*)d_in[7];
  const float* v_w = (const float*)d_in[8];
  const float* v_b = (const float*)d_in[9];
  const float* out_w = (const float*)d_in[10];
  const float* out_b = (const float*)d_in[11];
  float* out = (float*)d_out;

  u16* wq = (u16*)d_ws;                 // 256K f16 elems each (weights)
  u16* wk = wq + 262144;
  u16* wv = wk + 262144;
  u16* wo = wv + 262144;
  u16* Qbuf = wo + 262144;              // 4M f16 elems each
  u16* Kbuf = Qbuf + 4194304;
  u16* Vt   = Kbuf + 4194304;
  u16* ctxb = Vt + 4194304;

  CvtArgs ca;
  ca.src[0]=q_w;   ca.dst[0]=wq; ca.n4[0]=DM*DM/4;
  ca.src[1]=k_w;   ca.dst[1]=wk; ca.n4[1]=DM*DM/4;
  ca.src[2]=v_w;   ca.dst[2]=wv; ca.n4[2]=DM*DM/4;
  ca.src[3]=out_w; ca.dst[3]=wo; ca.n4[3]=DM*DM/4;
  cvt_kernel<<<dim3(64,4),256,0,stream>>>(ca);

  QkvArgs qa;
  qa.A[0]=query; qa.A[1]=key; qa.A[2]=value;
  qa.W[0]=wq; qa.W[1]=wk; qa.W[2]=wv;
  qa.bias[0]=q_b; qa.bias[1]=k_b; qa.bias[2]=v_b;
  qa.dst[0]=Qbuf; qa.dst[1]=Kbuf; qa.dst[2]=Vt;
  qa.scale[0]=0.0625f; qa.scale[1]=1.0f; qa.scale[2]=1.0f; // 1/8 (dh^-0.5) * 1/2 on Q

  proj_qkv<<<dim3(64,12),256,0,stream>>>(qa);

  attn_entmax<<<dim3(2048),512,0,stream>>>(Qbuf, Kbuf, Vt, maskp, ctxb);

  proj_out<<<dim3(128,4),256,0,stream>>>(ctxb, wo, out_b, out);
}

// Round 21
// 167.094 us; speedup vs baseline: 1.3767x; 1.0013x over previous
//
#include <hip/hip_runtime.h>
#include <stdint.h>

typedef _Float16 f16;
typedef __attribute__((ext_vector_type(8))) f16 f16x8;
typedef __attribute__((ext_vector_type(2))) f16 h2;
typedef __attribute__((ext_vector_type(4))) float f32x4;
typedef unsigned short u16;
typedef unsigned int u32;
typedef unsigned char u8;

#define LL 1024
#define DM 512

__device__ __forceinline__ u16 f2h(float f){ return __builtin_bit_cast(u16, (f16)f); }
__device__ __forceinline__ u32 pack2(float a, float b){
  h2 v; v.x = (f16)a; v.y = (f16)b; return __builtin_bit_cast(u32, v);
}
__device__ __forceinline__ f32x4 mfma16h(f16x8 a, f16x8 b, f32x4 c){
  return __builtin_amdgcn_mfma_f32_16x16x32_f16(a, b, c, 0, 0, 0);
}
// load 8 consecutive f32, convert to 8 packed f16 (RNE)
__device__ __forceinline__ uint4 ldcvt8(const float* p){
  float4 a = *(const float4*)p;
  float4 b = *(const float4*)(p+4);
  uint4 r;
  r.x = pack2(a.x,a.y); r.y = pack2(a.z,a.w);
  r.z = pack2(b.x,b.y); r.w = pack2(b.z,b.w);
  return r;
}

// ---- DPP 16-lane reductions (row_ror:8/4/2/1), pure VALU, no DS ----
template<int CTRL>
__device__ __forceinline__ float dpp_mov(float x){
  return __builtin_bit_cast(float,
    __builtin_amdgcn_update_dpp(0, __builtin_bit_cast(int, x), CTRL, 0xF, 0xF, true));
}
__device__ __forceinline__ float red_add16(float v){
  v += dpp_mov<0x128>(v);
  v += dpp_mov<0x124>(v);
  v += dpp_mov<0x122>(v);
  v += dpp_mov<0x121>(v);
  return v;
}
__device__ __forceinline__ float red_max16(float v){
  v = fmaxf(v, dpp_mov<0x128>(v));
  v = fmaxf(v, dpp_mov<0x124>(v));
  v = fmaxf(v, dpp_mov<0x122>(v));
  v = fmaxf(v, dpp_mov<0x121>(v));
  return v;
}

// ---------------- fp32 -> f16 convert (weights only, 2 MB) ----------
struct CvtArgs {
  const float* src[4];
  u16* dst[4];
  int n4[4];
};

__global__ __launch_bounds__(256) void cvt_kernel(CvtArgs a){
  int seg = blockIdx.y;
  const float4* s = (const float4*)a.src[seg];
  ushort4* d = (ushort4*)a.dst[seg];
  int n4 = a.n4[seg];
  for (int i = blockIdx.x*blockDim.x + threadIdx.x; i < n4; i += gridDim.x*blockDim.x){
    float4 v = s[i];
    ushort4 o;
    o.x = f2h(v.x); o.y = f2h(v.y); o.z = f2h(v.z); o.w = f2h(v.w);
    d[i] = o;
  }
}

// ---------------- fused QKV projection GEMM, 128x128 tile, BK=64 ----------------
// grid (64, 12): which = y>>2 (0=Q,1=K,2=V), nt = y&3.
// A = fp32 input, converted during register staging. W = f16 via global_load_lds.
struct QkvArgs {
  const float* A[3];
  const u16* W[3];
  const float* bias[3];
  u16* dst[3];
  float scale[3];
};

__global__ __launch_bounds__(256,2) void proj_qkv(QkvArgs args){
  __shared__ u16 SM[128*128];          // 32 KiB: As(16K)+Bs(16K), reused as stage
  u16* As = SM;
  u16* Bs = SM + 128*64;
  const int tid = threadIdx.x;
  const int w = tid>>6, lane = tid&63;
  const int g = lane>>4, r16 = lane&15;
  const int wr = w>>1, wc = w&1;

  const int which = blockIdx.y>>2, nt = blockIdx.y&3;
  const bool isV = (which==2);
  const float* A = args.A[which];
  const u16* W = args.W[which];
  const float* bias = args.bias[which];
  u16* dsth = args.dst[which];
  const float scale = args.scale[which];

  const int m0 = blockIdx.x*128, n0 = nt*128;

  f32x4 acc[4][4] = {};

  int rowc[4], slc[4];
  #pragma unroll
  for (int i=0;i<4;++i){
    int c = i*256+tid;
    rowc[i] = c>>3;
    slc[i] = (c&7) ^ ((c>>3)&7);
  }

  const int fswz = r16 & 7;

  for (int k0=0; k0<DM; k0+=64){
    uint4 av[4];
    #pragma unroll
    for (int i=0;i<4;++i)
      av[i] = ldcvt8(A + (size_t)(m0+rowc[i])*DM + k0 + slc[i]*8);
    #pragma unroll
    for (int i=0;i<4;++i){
      int c = i*256+tid;
      __builtin_amdgcn_global_load_lds(
        (const __attribute__((address_space(1))) void*)(W + (size_t)(n0+rowc[i])*DM + k0 + slc[i]*8),
        (__attribute__((address_space(3))) void*)(&Bs[c*8]), 16, 0, 0);
    }
    #pragma unroll
    for (int i=0;i<4;++i)
      *(uint4*)(&As[(i*256+tid)*8]) = av[i];
    __syncthreads();   // drains vmcnt + lgkm -> staged LDS ready

    f16x8 af[4][2], bfr[4][2];
    #pragma unroll
    for (int mi=0; mi<4; ++mi){
      int row = wr*64 + mi*16 + r16;
      #pragma unroll
      for (int ks=0; ks<2; ++ks)
        af[mi][ks] = *(const f16x8*)(&As[row*64 + ((ks*4+g)^fswz)*8]);
    }
    #pragma unroll
    for (int ni=0; ni<4; ++ni){
      int row = wc*64 + ni*16 + r16;
      #pragma unroll
      for (int ks=0; ks<2; ++ks)
        bfr[ni][ks] = *(const f16x8*)(&Bs[row*64 + ((ks*4+g)^fswz)*8]);
    }
    if (isV){
      #pragma unroll
      for (int mi=0; mi<4; ++mi)
        #pragma unroll
        for (int ni=0; ni<4; ++ni){
          acc[mi][ni] = mfma16h(af[mi][0], bfr[ni][0], acc[mi][ni]);
          acc[mi][ni] = mfma16h(af[mi][1], bfr[ni][1], acc[mi][ni]);
        }
    } else {
      #pragma unroll
      for (int mi=0; mi<4; ++mi)
        #pragma unroll
        for (int ni=0; ni<4; ++ni){
          acc[mi][ni] = mfma16h(bfr[ni][0], af[mi][0], acc[mi][ni]);
          acc[mi][ni] = mfma16h(bfr[ni][1], af[mi][1], acc[mi][ni]);
        }
    }
    __syncthreads();   // all reads done before next stage overwrites
  }

  // ---- epilogue: stage into chunk-swizzled LDS, then coalesced stores
  if (!isV){
    #pragma unroll
    for (int mi=0; mi<4; ++mi){
      #pragma unroll
      for (int ni=0; ni<4; ++ni){
        f32x4 a = acc[mi][ni];
        int row = wr*64 + mi*16 + r16;
        int c   = wc*16 + ni*4 + g;
        float4 bv = *(const float4*)(bias + n0 + c*4);
        uint2 pk;
        pk.x = pack2((a[0]+bv.x)*scale, (a[1]+bv.y)*scale);
        pk.y = pack2((a[2]+bv.z)*scale, (a[3]+bv.w)*scale);
        *(uint2*)(&SM[row*128 + ((c ^ ((row&7)<<2))<<2)]) = pk;
      }
    }
  } else {
    #pragma unroll
    for (int mi=0; mi<4; ++mi){
      #pragma unroll
      for (int ni=0; ni<4; ++ni){
        f32x4 a = acc[mi][ni];
        int fl = wc*64 + ni*16 + r16;
        int kc = wr*16 + mi*4 + g;
        float bv = bias[n0 + fl];
        uint2 pk;
        pk.x = pack2(a[0]+bv, a[1]+bv);
        pk.y = pack2(a[2]+bv, a[3]+bv);
        *(uint2*)(&SM[fl*128 + ((kc ^ ((fl&7)<<2))<<2)]) = pk;
      }
    }
  }
  __syncthreads();

  #pragma unroll
  for (int rr=0; rr<8; ++rr){
    int row = w*32 + rr*4 + (lane>>4);
    int c0 = (lane&15)*2;
    int cs = c0 ^ ((row&7)<<2);
    uint4 v = *(const uint4*)(&SM[row*128 + (cs<<2)]);
    if (!isV){
      *(uint4*)(dsth + (size_t)(m0+row)*DM + n0 + (c0<<2)) = v;
    } else {
      int n = n0 + row;
      int hh = n>>6, d = n&63, bb = m0>>10;
      *(uint4*)(dsth + (size_t)((bb*8+hh)*64 + d)*1024 + (m0&1023) + (c0<<2)) = v;
    }
  }
}

// ---------------- out-projection GEMM, 64x128 tile, BK=64, grid (128,4) ----------------
__global__ __launch_bounds__(256,2) void proj_out(
    const u16* __restrict__ A, const u16* __restrict__ W,
    const float* __restrict__ bias, float* __restrict__ dstf)
{
  __shared__ u16 As[64*64];
  __shared__ u16 Bs[128*64];
  const int tid = threadIdx.x;
  const int w = tid>>6, lane = tid&63;
  const int g = lane>>4, r16 = lane&15;
  const int m0 = blockIdx.x*64, n0 = blockIdx.y*128;

  f32x4 acc[4][2] = {};

  int rowa[2], slota[2];
  #pragma unroll
  for (int i=0;i<2;++i){ int c = i*256+tid; rowa[i]=c>>3; slota[i]=c&7; }
  int rowb[4], slotb[4];
  #pragma unroll
  for (int i=0;i<4;++i){ int c = i*256+tid; rowb[i]=c>>3; slotb[i]=c&7; }

  uint4 ra[2], rb[4];
  #pragma unroll
  for (int i=0;i<2;++i)
    ra[i] = *(const uint4*)(A + (size_t)(m0+rowa[i])*DM + slota[i]*8);
  #pragma unroll
  for (int i=0;i<4;++i)
    rb[i] = *(const uint4*)(W + (size_t)(n0+rowb[i])*DM + slotb[i]*8);

  const int fswz = r16 & 7;

  for (int k0=0; k0<DM; k0+=64){
    __syncthreads();
    #pragma unroll
    for (int i=0;i<2;++i)
      *(uint4*)(&As[rowa[i]*64 + (slota[i]^(rowa[i]&7))*8]) = ra[i];
    #pragma unroll
    for (int i=0;i<4;++i)
      *(uint4*)(&Bs[rowb[i]*64 + (slotb[i]^(rowb[i]&7))*8]) = rb[i];
    __syncthreads();
    int kn = (k0+64 < DM) ? (k0+64) : 0;
    #pragma unroll
    for (int i=0;i<2;++i)
      ra[i] = *(const uint4*)(A + (size_t)(m0+rowa[i])*DM + kn + slota[i]*8);
    #pragma unroll
    for (int i=0;i<4;++i)
      rb[i] = *(const uint4*)(W + (size_t)(n0+rowb[i])*DM + kn + slotb[i]*8);

    f16x8 af[4][2], bfr[2][2];
    #pragma unroll
    for (int mi=0; mi<4; ++mi){
      int row = mi*16 + r16;
      #pragma unroll
      for (int ks=0; ks<2; ++ks)
        af[mi][ks] = *(const f16x8*)(&As[row*64 + ((ks*4+g)^fswz)*8]);
    }
    #pragma unroll
    for (int ni=0; ni<2; ++ni){
      int row = w*32 + ni*16 + r16;
      #pragma unroll
      for (int ks=0; ks<2; ++ks)
        bfr[ni][ks] = *(const f16x8*)(&Bs[row*64 + ((ks*4+g)^fswz)*8]);
    }
    #pragma unroll
    for (int mi=0; mi<4; ++mi)
      #pragma unroll
      for (int ni=0; ni<2; ++ni){
        acc[mi][ni] = mfma16h(bfr[ni][0], af[mi][0], acc[mi][ni]);
        acc[mi][ni] = mfma16h(bfr[ni][1], af[mi][1], acc[mi][ni]);
      }
  }

  #pragma unroll
  for (int mi=0; mi<4; ++mi){
    #pragma unroll
    for (int ni=0; ni<2; ++ni){
      int m  = m0 + mi*16 + r16;
      int nb = n0 + w*32 + ni*16 + g*4;
      float4 bv = *(const float4*)(bias + nb);
      float4 o;
      o.x = acc[mi][ni][0]+bv.x; o.y = acc[mi][ni][1]+bv.y;
      o.z = acc[mi][ni][2]+bv.z; o.w = acc[mi][ni][3]+bv.w;
      *(float4*)(dstf + (size_t)m*DM + nb) = o;
    }
  }
}

// ---------------- fused attention + entmax-1.5 (r19, session optimum) ----------
// grid 2048, 512 threads (8 waves): bh = ((bid&7)<<3)|((bid>>3)&7), qb = bid>>6.
// 32 q-rows/block, S[32][1024] f16 = 64 KiB (2 blocks/CU).
// Phase A: 16-load K burst + sched_barrier(0) pin (r17: -10us).
// Newton 5 iters + finalize — VERIFIED MINIMUM (r20: 4 iters -> absmax 0.021
// FAIL; support-set misclassification is discontinuous, renorm can't absorb).
// Swizzle: (row,k) at u16 off row*1024 + (k^(cc<<3)), cc = ((k>>6)&7) ^ (row&7).
__global__ __launch_bounds__(512,4) void attn_entmax(
    const u16* __restrict__ Qf, const u16* __restrict__ Kf,
    const u16* __restrict__ Vt, const u8* __restrict__ mask,
    u16* __restrict__ ctx)
{
  __shared__ u16 S[32*1024];   // 64 KiB

  const int tid = threadIdx.x, w = tid>>6, lane = tid&63;
  const int g = lane>>4, r16 = lane&15;
  const int bid = blockIdx.x;
  const int bh = ((bid&7)<<3) | ((bid>>3)&7);
  const int qb = bid>>6;
  const int b = bh>>3, h = bh&7;
  const int q0 = qb*32;
  const u16* Qb = Qf + ((size_t)(b*LL + q0))*DM + h*64;
  const u16* Kb = Kf + ((size_t)(b*LL))*DM + h*64;

  // ---- Phase A: S^T = K Q^T (scale folded into Q); wave w: keys [w*128,+128)
  f16x8 qf[2][2];
  #pragma unroll
  for (int qi=0;qi<2;++qi){
    qf[qi][0] = *(const f16x8*)(Qb + (size_t)(qi*16 + r16)*DM + g*8);
    qf[qi][1] = *(const f16x8*)(Qb + (size_t)(qi*16 + r16)*DM + 32 + g*8);
  }
  {
    f16x8 kr0[8], kr1[8];
    u32 m4a[8];
    #pragma unroll
    for (int kt=0;kt<8;++kt){
      const u16* kp = Kb + (size_t)(w*128 + kt*16 + r16)*DM + g*8;
      kr0[kt] = *(const f16x8*)(kp);
      kr1[kt] = *(const f16x8*)(kp + 32);
      m4a[kt] = *(const u32*)(mask + b*LL + w*128 + kt*16 + g*4);
    }
    __builtin_amdgcn_sched_barrier(0);   // pin: all 16 loads issued before use
    #pragma unroll
    for (int kt=0;kt<8;++kt){
      int kb = w*128 + kt*16 + g*4;
      u32 m4 = m4a[kt];
      #pragma unroll
      for (int qi=0; qi<2; ++qi){
        f32x4 acc = {};
        acc = mfma16h(kr0[kt], qf[qi][0], acc);   // reg-dim: key, col: q=r16
        acc = mfma16h(kr1[kt], qf[qi][1], acc);
        float v0 = (m4 & 0xFFu)       ? -30000.f : acc[0];
        float v1 = (m4 & 0xFF00u)     ? -30000.f : acc[1];
        float v2 = (m4 & 0xFF0000u)   ? -30000.f : acc[2];
        float v3 = (m4 & 0xFF000000u) ? -30000.f : acc[3];
        int row = qi*16 + r16;
        int cc = ((kb>>6)&7) ^ (row&7);
        uint2 pk; pk.x = pack2(v0,v1); pk.y = pack2(v2,v3);
        *(uint2*)(&S[row*LL + (kb ^ (cc<<3))]) = pk;
      }
    }
  }
  __syncthreads();

  // ---- Phase B: entmax-1.5; row = w*4+g (4 rows/wave in parallel),
  // lane r16 holds 64 contiguous keys as 32 h2; all-DPP reduces; 5 Newton iters.
  {
    const int r = w*4 + g;
    const int ccb = (r16 ^ r) & 7;
    h2 zp[32];
    #pragma unroll
    for (int c=0;c<8;++c){
      uint4 v = *(const uint4*)(&S[r*LL + ((r16*64 + c*8) ^ (ccb<<3))]);
      zp[c*4+0] = __builtin_bit_cast(h2, v.x);
      zp[c*4+1] = __builtin_bit_cast(h2, v.y);
      zp[c*4+2] = __builtin_bit_cast(h2, v.z);
      zp[c*4+3] = __builtin_bit_cast(h2, v.w);
    }
    __builtin_amdgcn_sched_barrier(0);   // pin: all 8 ds_read_b128 in flight
    h2 m2 = zp[0];
    #pragma unroll
    for (int t=1;t<32;++t) m2 = __builtin_elementwise_max(m2, zp[t]);
    float mx = red_max16(fmaxf((float)m2.x, (float)m2.y));

    const h2 zero2 = (h2)(f16)0;
    float lo = mx - 1.0f, hi = mx, tau = mx - 0.5f;
    #pragma unroll 1
    for (int it=0; it<5; ++it){
      f16 th = (f16)tau;
      h2 t2; t2.x = th; t2.y = th;
      h2 s1a = zero2, s1b = zero2, s2a = zero2, s2b = zero2;
      #pragma unroll
      for (int t=0;t<32;t+=2){
        h2 d0 = __builtin_elementwise_max(zp[t]   - t2, zero2);
        h2 d1 = __builtin_elementwise_max(zp[t+1] - t2, zero2);
        s1a = s1a + d0;        s1b = s1b + d1;
        s2a = s2a + d0*d0;     s2b = s2b + d1*d1;
      }
      h2 s1h = s1a + s1b, s2h = s2a + s2b;
      float s1 = red_add16((float)s1h.x + (float)s1h.y);
      float s2 = red_add16((float)s2h.x + (float)s2h.y);
      if (s2 >= 1.0f) lo = tau; else hi = tau;
      float tn = tau + (s2 - 1.0f)/(2.0f*s1);
      tau = (tn >= lo && tn < hi) ? tn : 0.5f*(lo+hi);
    }

    {
      f16 th = (f16)tau;
      h2 t2; t2.x = th; t2.y = th;
      h2 psa = zero2, psb = zero2;
      #pragma unroll
      for (int t=0;t<32;t+=2){
        h2 d0 = __builtin_elementwise_max(zp[t]   - t2, zero2);
        h2 d1 = __builtin_elementwise_max(zp[t+1] - t2, zero2);
        h2 p0 = d0*d0, p1 = d1*d1;
        zp[t] = p0; zp[t+1] = p1;
        psa = psa + p0; psb = psb + p1;
      }
      h2 ps2 = psa + psb;
      float ps = red_add16((float)ps2.x + (float)ps2.y);
      f16 iv = (f16)(1.0f/ps);
      h2 i2; i2.x = iv; i2.y = iv;
      #pragma unroll
      for (int c=0;c<8;++c){
        uint4 v;
        v.x = __builtin_bit_cast(u32, (h2)(zp[c*4+0]*i2));
        v.y = __builtin_bit_cast(u32, (h2)(zp[c*4+1]*i2));
        v.z = __builtin_bit_cast(u32, (h2)(zp[c*4+2]*i2));
        v.w = __builtin_bit_cast(u32, (h2)(zp[c*4+3]*i2));
        *(uint4*)(&S[r*LL + ((r16*64 + c*8) ^ (ccb<<3))]) = v;  // same slots read
      }
    }
  }
  __syncthreads();

  // ---- Phase C: ctx = P @ V ; wave w -> q-tile (w>>2), d-tile (w&3);
  // P(LDS) + V(L2) loads double-buffered 4 kt ahead, prefetch pinned.
  const int qi = w>>2, di = w&3;
  const u16* vrow = Vt + (size_t)(bh*64 + di*16 + r16)*LL;
  const int prow = qi*16 + r16;
  f32x4 o0 = {}, o1 = {};
  {
    f16x8 pc[4], vc[4], pn[4], vn[4];
    #pragma unroll
    for (int j=0;j<4;++j){
      int k = j*32 + g*8;
      int cc = ((k>>6)&7) ^ (prow&7);
      pc[j] = *(const f16x8*)(&S[prow*LL + (k ^ (cc<<3))]);
      vc[j] = *(const f16x8*)(vrow + k);
    }
    #pragma unroll
    for (int grp=0; grp<8; ++grp){
      #pragma unroll
      for (int j=0;j<4;++j){
        if (grp < 7){
          int k = (grp*4+4+j)*32 + g*8;
          int cc = ((k>>6)&7) ^ (prow&7);
          pn[j] = *(const f16x8*)(&S[prow*LL + (k ^ (cc<<3))]);
          vn[j] = *(const f16x8*)(vrow + k);
        }
      }
      __builtin_amdgcn_sched_barrier(0);  // pin: prefetch issued before MFMAs
      __builtin_amdgcn_s_setprio(1);
      #pragma unroll
      for (int j=0;j<4;++j){
        if (j & 1) o1 = mfma16h(pc[j], vc[j], o1);
        else       o0 = mfma16h(pc[j], vc[j], o0);
      }
      __builtin_amdgcn_s_setprio(0);
      #pragma unroll
      for (int j=0;j<4;++j){ pc[j]=pn[j]; vc[j]=vn[j]; }
    }
  }
  #pragma unroll
  for (int r=0;r<4;++r){
    int q = q0 + qi*16 + g*4 + r;
    ctx[(size_t)(b*LL + q)*DM + h*64 + di*16 + r16] = f2h(o0[r] + o1[r]);
  }
}

// ---------------- launch ----------------
extern "C" void kernel_launch(void* const* d_in, const int* in_sizes, int n_in,
                              void* d_out, int out_size, void* d_ws, size_t ws_size,
                              hipStream_t stream) {
  const float* query = (const float*)d_in[0];
  const float* key   = (const float*)d_in[1];
  const float* value = (const float*)d_in[2];
  const u8*    maskp = (const u8*)d_in[3];
  const float* q_w = (const float*)d_in[4];
  const float* q_b = (const float*)d_in[5];
  const float* k_w = (const float*)d_in[6];
  const float* k_b = (const float*)d_in[7];
  const float* v_w = (const float*)d_in[8];
  const float* v_b = (const float*)d_in[9];
  const float* out_w = (const float*)d_in[10];
  const float* out_b = (const float*)d_in[11];
  float* out = (float*)d_out;

  u16* wq = (u16*)d_ws;                 // 256K f16 elems each (weights)
  u16* wk = wq + 262144;
  u16* wv = wk + 262144;
  u16* wo = wv + 262144;
  u16* Qbuf = wo + 262144;              // 4M f16 elems each
  u16* Kbuf = Qbuf + 4194304;
  u16* Vt   = Kbuf + 4194304;
  u16* ctxb = Vt + 4194304;

  CvtArgs ca;
  ca.src[0]=q_w;   ca.dst[0]=wq; ca.n4[0]=DM*DM/4;
  ca.src[1]=k_w;   ca.dst[1]=wk; ca.n4[1]=DM*DM/4;
  ca.src[2]=v_w;   ca.dst[2]=wv; ca.n4[2]=DM*DM/4;
  ca.src[3]=out_w; ca.dst[3]=wo; ca.n4[3]=DM*DM/4;
  cvt_kernel<<<dim3(64,4),256,0,stream>>>(ca);

  QkvArgs qa;
  qa.A[0]=query; qa.A[1]=key; qa.A[2]=value;
  qa.W[0]=wq; qa.W[1]=wk; qa.W[2]=wv;
  qa.bias[0]=q_b; qa.bias[1]=k_b; qa.bias[2]=v_b;
  qa.dst[0]=Qbuf; qa.dst[1]=Kbuf; qa.dst[2]=Vt;
  qa.scale[0]=0.0625f; qa.scale[1]=1.0f; qa.scale[2]=1.0f; // 1/8 (dh^-0.5) * 1/2 on Q

  proj_qkv<<<dim3(64,12),256,0,stream>>>(qa);

  attn_entmax<<<dim3(2048),512,0,stream>>>(Qbuf, Kbuf, Vt, maskp, ctxb);

  proj_out<<<dim3(128,4),256,0,stream>>>(ctxb, wo, out_b, out);
}